// Round 1
// 1345.154 us; speedup vs baseline: 1.0610x; 1.0610x over previous
//
#include <hip/hip_runtime.h>
#include <stdint.h>

typedef unsigned short u16;
typedef __bf16 bf16x8 __attribute__((ext_vector_type(8)));
typedef float floatx4 __attribute__((ext_vector_type(4)));

#define HIDDEN 2560
#define NHEADS 32
#define HD 80
#define SEQ 2048
#define BATCH 2
#define MROWS (BATCH*SEQ)
#define QB 128

__device__ __forceinline__ float bf2f(uint32_t bits) {
    return __uint_as_float(bits << 16);
}
__device__ __forceinline__ u16 f2bf_bits(float f) {
    uint32_t x = __float_as_uint(f);
    uint32_t r = (x + 0x7fffu + ((x >> 16) & 1u)) >> 16;  // RTNE
    return (u16)r;
}
__device__ __forceinline__ floatx4 mk4(float x) {
    return (floatx4){x, x, x, x};
}
__device__ __forceinline__ floatx4 max4(floatx4 a, floatx4 b) {
    floatx4 r;
#pragma unroll
    for (int i = 0; i < 4; i++) r[i] = fmaxf(a[i], b[i]);
    return r;
}
__device__ __forceinline__ floatx4 exp4(floatx4 a) {
    floatx4 r;
#pragma unroll
    for (int i = 0; i < 4; i++) r[i] = __expf(a[i]);
    return r;
}
__device__ __forceinline__ floatx4 shfl_xor4(floatx4 v, int mask) {
    floatx4 r;
#pragma unroll
    for (int i = 0; i < 4; i++) r[i] = __shfl_xor(v[i], mask, 64);
    return r;
}
// async global->LDS, 16B per lane; dest is wave-uniform base + lane*16 (linear)
__device__ __forceinline__ void gload16(const u16* g, u16* l) {
    __builtin_amdgcn_global_load_lds(
        (const __attribute__((address_space(1))) uint32_t*)g,
        (__attribute__((address_space(3))) uint32_t*)l, 16, 0, 0);
}

// ---------------- split fp32 -> bf16 hi/lo, elementwise ---------------------------
__global__ __launch_bounds__(256) void split_x(const float* __restrict__ in,
                                               u16* __restrict__ hi,
                                               u16* __restrict__ lo) {
    size_t i4 = (size_t)blockIdx.x * 256 + threadIdx.x;
    float4 v = ((const float4*)in)[i4];
    float f[4] = {v.x, v.y, v.z, v.w};
    u16 h[4], l[4];
#pragma unroll
    for (int j = 0; j < 4; j++) {
        h[j] = f2bf_bits(f[j]);
        l[j] = f2bf_bits(f[j] - bf2f(h[j]));
    }
    ((uint2*)hi)[i4] = *(uint2*)h;
    ((uint2*)lo)[i4] = *(uint2*)l;
}

// ------------- transpose + split: W[k][n] fp32 -> WT hi/lo bf16 [n][k] ------------
__global__ __launch_bounds__(256) void split_wt(const float* __restrict__ in,
                                                u16* __restrict__ outh,
                                                u16* __restrict__ outl) {
    __shared__ float t[64][65];
    int k0 = blockIdx.x * 64;
    int n0 = blockIdx.y * 64;
    int tid = threadIdx.x;
    int rr = tid >> 4;
    int c4 = (tid & 15) * 4;
#pragma unroll
    for (int it = 0; it < 4; it++) {
        int row = it * 16 + rr;
        float4 v = *(const float4*)&in[(size_t)(k0 + row) * HIDDEN + n0 + c4];
        t[row][c4 + 0] = v.x; t[row][c4 + 1] = v.y;
        t[row][c4 + 2] = v.z; t[row][c4 + 3] = v.w;
    }
    __syncthreads();
#pragma unroll
    for (int it = 0; it < 4; it++) {
        int row = it * 16 + rr;
        float f[4] = { t[c4 + 0][row], t[c4 + 1][row], t[c4 + 2][row], t[c4 + 3][row] };
        u16 h[4], l[4];
#pragma unroll
        for (int j = 0; j < 4; j++) {
            h[j] = f2bf_bits(f[j]);
            l[j] = f2bf_bits(f[j] - bf2f(h[j]));
        }
        size_t o = (size_t)(n0 + row) * HIDDEN + k0 + c4;
        *(uint2*)&outh[o] = *(uint2*)h;
        *(uint2*)&outl[o] = *(uint2*)l;
    }
}

// ------- GEMM: C[M][N] = A[M][K] * Bt[N][K]^T, pre-split bf16 in, fp32 out --------
// Staging via global_load_lds (width 16) into linear [128][32] u16 buffers.
// Bank-conflict-free reads via XOR swizzle: physical slot = lq ^ ((row>>1)&3),
// with the inverse swizzle pre-applied to the per-lane GLOBAL source address
// (global_load_lds dest must stay linear — rule: both-sides-or-neither).
__global__ __launch_bounds__(256) void gemm_bt2(const u16* __restrict__ Ah,
                                                const u16* __restrict__ Al,
                                                const u16* __restrict__ Bh,
                                                const u16* __restrict__ Bl,
                                                float* __restrict__ C) {
    __shared__ u16 lAh[128 * 32];
    __shared__ u16 lAl[128 * 32];
    __shared__ u16 lBh[128 * 32];
    __shared__ u16 lBl[128 * 32];
    const int K = HIDDEN;
    int tid  = threadIdx.x;
    int lane = tid & 63;
    int wave = tid >> 6;
    int wr = wave >> 1, wc = wave & 1;
    int m0 = blockIdx.y * 128, n0 = blockIdx.x * 128;
    int lr = lane & 15, lq = lane >> 4;

    // staging geometry: wave w stages rows [w*32, w*32+32) of every buffer,
    // as two 16-row global_load_lds per buffer (lane i -> row base+(i>>2), slot i&3).
    int srow = wave * 32 + (lane >> 2);                       // rows for q=0 (q=1: +16)
    int scol = ((lane & 3) ^ ((lane >> 3) & 3)) * 8;          // inverse-swizzled u16 col
    const u16* gAh = Ah + (size_t)(m0 + srow) * K + scol;
    const u16* gAl = Al + (size_t)(m0 + srow) * K + scol;
    const u16* gBh = Bh + (size_t)(n0 + srow) * K + scol;
    const u16* gBl = Bl + (size_t)(n0 + srow) * K + scol;
    const size_t q1 = (size_t)16 * K;                          // +16 rows
    u16* dAh = &lAh[(wave * 32) * 32];
    u16* dAl = &lAl[(wave * 32) * 32];
    u16* dBh = &lBh[(wave * 32) * 32];
    u16* dBl = &lBl[(wave * 32) * 32];

    floatx4 acc[4][4];
#pragma unroll
    for (int i = 0; i < 4; i++)
#pragma unroll
        for (int j = 0; j < 4; j++)
            acc[i][j] = mk4(0.f);

    int swz = (lr >> 1) & 3;          // read-side swizzle (row&15 == lr for all frags)
    int rsl = (lq ^ swz) * 8;

    for (int k0 = 0; k0 < K; k0 += 32) {
        gload16(gAh + k0, dAh);  gload16(gAh + q1 + k0, dAh + 16 * 32);
        gload16(gAl + k0, dAl);  gload16(gAl + q1 + k0, dAl + 16 * 32);
        gload16(gBh + k0, dBh);  gload16(gBh + q1 + k0, dBh + 16 * 32);
        gload16(gBl + k0, dBl);  gload16(gBl + q1 + k0, dBl + 16 * 32);
        __syncthreads();            // compiler drains vmcnt(0) before s_barrier
        bf16x8 ah[4], al[4], bh[4], bl[4];
#pragma unroll
        for (int i = 0; i < 4; i++) {
            int ra = (wr * 64 + i * 16 + lr) * 32 + rsl;
            int rb = (wc * 64 + i * 16 + lr) * 32 + rsl;
            ah[i] = *(const bf16x8*)&lAh[ra];
            al[i] = *(const bf16x8*)&lAl[ra];
            bh[i] = *(const bf16x8*)&lBh[rb];
            bl[i] = *(const bf16x8*)&lBl[rb];
        }
#pragma unroll
        for (int i = 0; i < 4; i++)
#pragma unroll
            for (int j = 0; j < 4; j++) {
                acc[i][j] = __builtin_amdgcn_mfma_f32_16x16x32_bf16(ah[i], bh[j], acc[i][j], 0, 0, 0);
                acc[i][j] = __builtin_amdgcn_mfma_f32_16x16x32_bf16(ah[i], bl[j], acc[i][j], 0, 0, 0);
                acc[i][j] = __builtin_amdgcn_mfma_f32_16x16x32_bf16(al[i], bh[j], acc[i][j], 0, 0, 0);
            }
        __syncthreads();
    }
#pragma unroll
    for (int i = 0; i < 4; i++) {
        int rowb = m0 + wr * 64 + i * 16 + lq * 4;
#pragma unroll
        for (int j = 0; j < 4; j++) {
            int col = n0 + wc * 64 + j * 16 + lr;
#pragma unroll
            for (int r = 0; r < 4; r++)
                C[(size_t)(rowb + r) * HIDDEN + col] = acc[i][j][r];
        }
    }
}

// ---------------- RoPE (ROT=20 -> 10 pairs) on Q and K, in place, fp32 -----------
__global__ __launch_bounds__(256) void rope_k(float* __restrict__ Qb, float* __restrict__ Kb,
                                              const int* __restrict__ pos_ids) {
    int idx = blockIdx.x * 256 + threadIdx.x;
    int row = idx >> 5;
    int h   = idx & 31;
    float pos = (float)pos_ids[row];
    size_t base = (size_t)row * HIDDEN + h * HD;
    float* q = Qb + base;
    float* k = Kb + base;
#pragma unroll
    for (int i = 0; i < 10; i++) {
        float freq = pos * exp2f(-1.3287712379549449f * (float)i);
        float sn, cs;
        sincosf(freq, &sn, &cs);
        float q1 = q[i], q2 = q[i + 10];
        q[i]      = q1 * cs - q2 * sn;
        q[i + 10] = q2 * cs + q1 * sn;
        float k1 = k[i], k2 = k[i + 10];
        k[i]      = k1 * cs - k2 * sn;
        k[i + 10] = k2 * cs + k1 * sn;
    }
}

// ---- V transpose+split: Vb fp32 [b*S+s][2560] -> Vth/Vtl u16 [bh][d(80)][s(2048)]
__global__ __launch_bounds__(256) void vtrans(const float* __restrict__ Vb,
                                              u16* __restrict__ Vth,
                                              u16* __restrict__ Vtl) {
    __shared__ float t[64][81];
    int bh = blockIdx.x; int b = bh >> 5, h = bh & 31;
    int s0 = blockIdx.y * 64;
    int tid = threadIdx.x;
    for (int idx = tid; idx < 64 * 20; idx += 256) {
        int s = idx / 20, c = idx % 20;
        float4 v = *(const float4*)&Vb[(size_t)(b * SEQ + s0 + s) * HIDDEN + h * HD + c * 4];
        t[s][c * 4 + 0] = v.x; t[s][c * 4 + 1] = v.y;
        t[s][c * 4 + 2] = v.z; t[s][c * 4 + 3] = v.w;
    }
    __syncthreads();
    for (int idx = tid; idx < 80 * 8; idx += 256) {
        int d = idx >> 3, sc = idx & 7;
        u16 hh[8], ll[8];
#pragma unroll
        for (int j = 0; j < 8; j++) {
            float f = t[sc * 8 + j][d];
            hh[j] = f2bf_bits(f);
            ll[j] = f2bf_bits(f - bf2f(hh[j]));
        }
        size_t o = ((size_t)bh * HD + d) * SEQ + s0 + sc * 8;
        *(int4*)&Vth[o] = *(int4*)hh;
        *(int4*)&Vtl[o] = *(int4*)ll;
    }
}

// ---------------- MFMA flash attention ------------------------------------------
// block: 128 queries of one (b,h); 4 waves x 32 queries (2 row-tiles of 16).
// K tiles: 32 keys, split bf16 hi/lo in LDS [key][96pad->pitch104].
// V tiles: from pre-transposed Vth/Vtl, LDS [dim(80)][key(32)] pitch 40.
// S = QK^T 3-pass split; P bf16 via wave-private LDS tile; PV 2-pass (Vh+Vl).
__global__ __launch_bounds__(256) void attn_mfma(const u16* __restrict__ Qh_,
                                                 const u16* __restrict__ Ql_,
                                                 const u16* __restrict__ Kh_,
                                                 const u16* __restrict__ Kl_,
                                                 const u16* __restrict__ Vth_,
                                                 const u16* __restrict__ Vtl_,
                                                 u16* __restrict__ Oh_,
                                                 u16* __restrict__ Ol_) {
    __shared__ u16 lds[15616];          // 31232 B
    u16* lKh = lds;                     // 32*104
    u16* lKl = lds + 3328;              // 32*104
    u16* lVh = lds + 6656;              // 80*40
    u16* lVl = lds + 9856;              // 80*40
    u16* lP  = lds + 13056;             // 4 waves * 16*40

    int tid = threadIdx.x;
    int lane = tid & 63, w = tid >> 6;
    int lr = lane & 15, lq = lane >> 4;
    int bh = blockIdx.x; int b = bh >> 5, h = bh & 31;
    int qblk = (gridDim.y - 1) - blockIdx.y;   // long blocks dispatched first
    int q0 = qblk * QB;
    size_t rowbase = (size_t)b * SEQ;
    size_t hoff = (size_t)h * HD;
    const float SC = 0.11180339887498949f;     // 1/sqrt(80)

    // ---- stage Q (two rounds of 64 rows through overlay region) -> A-frags ----
    bf16x8 qh[2][3], ql[2][3];
#pragma unroll
    for (int round = 0; round < 2; round++) {
        for (int idx = tid; idx < 1280; idx += 256) {
            int buf = idx >= 640; int e = idx - buf * 640;
            int r = e / 10, c = e % 10;
            const u16* src = (buf ? Ql_ : Qh_) +
                (rowbase + q0 + round * 64 + r) * HIDDEN + hoff + c * 8;
            *(int4*)&lds[buf * 6656 + r * 104 + c * 8] = *(const int4*)src;
        }
        {   // zero pad cols 80..95
            int idx = tid;
            if (idx < 256) {
                int buf = idx >= 128; int e = idx - buf * 128;
                int r = e >> 1, hf = e & 1;
                *(int4*)&lds[buf * 6656 + r * 104 + 80 + hf * 8] = make_int4(0, 0, 0, 0);
            }
        }
        __syncthreads();
        if ((w >> 1) == round) {
            int wl = w & 1;
#pragma unroll
            for (int rt = 0; rt < 2; rt++) {
                int lrow = wl * 32 + rt * 16 + lr;
#pragma unroll
                for (int c = 0; c < 3; c++) {
                    qh[rt][c] = *(const bf16x8*)&lds[lrow * 104 + c * 32 + lq * 8];
                    ql[rt][c] = *(const bf16x8*)&lds[6656 + lrow * 104 + c * 32 + lq * 8];
                }
            }
        }
        __syncthreads();
    }
    // zero K pad cols 80..95 (persists across tiles; staging only writes 0..79)
    if (tid < 128) {
        int buf = tid >= 64; int e = tid - buf * 64;
        int r = e >> 1, hf = e & 1;
        *(int4*)&lds[buf * 3328 + r * 104 + 80 + hf * 8] = make_int4(0, 0, 0, 0);
    }

    floatx4 acc[2][5];
    floatx4 mrow[2], lsum[2];
#pragma unroll
    for (int rt = 0; rt < 2; rt++) {
        mrow[rt] = mk4(-3.0e38f);
        lsum[rt] = mk4(0.f);
#pragma unroll
        for (int nt = 0; nt < 5; nt++) acc[rt][nt] = mk4(0.f);
    }

    int ntiles = 4 * qblk + 4;
    int qw0 = q0 + w * 32;
    u16* lPw = lP + w * 640;

    for (int t = 0; t < ntiles; t++) {
        int k0 = t * 32;
        // ---- stage K (hi/lo) and V (hi/lo): 1280 int4 / 256 threads ----
        for (int idx = tid; idx < 1280; idx += 256) {
            if (idx < 640) {
                int buf = idx >= 320; int e = idx - buf * 320;
                int r = e / 10, c = e % 10;
                const u16* src = (buf ? Kl_ : Kh_) +
                    (rowbase + k0 + r) * HIDDEN + hoff + c * 8;
                *(int4*)&lds[buf * 3328 + r * 104 + c * 8] = *(const int4*)src;
            } else {
                int e2 = idx - 640;
                int buf = e2 >= 320; int e = e2 - buf * 320;
                int d = e >> 2, kc = e & 3;
                const u16* src = (buf ? Vtl_ : Vth_) +
                    ((size_t)bh * HD + d) * SEQ + k0 + kc * 8;
                *(int4*)&lds[6656 + buf * 3200 + d * 40 + kc * 8] = *(const int4*)src;
            }
        }
        __syncthreads();
        if (k0 <= qw0 + 31) {
#pragma unroll
            for (int rt = 0; rt < 2; rt++) {
                int qrt0 = qw0 + rt * 16;
                if (k0 > qrt0 + 15) continue;
                // ---- S = Q K^T (two 16-key subtiles, 3-pass split) ----
                floatx4 s[2];
#pragma unroll
                for (int st = 0; st < 2; st++) {
                    floatx4 sv = mk4(0.f);
#pragma unroll
                    for (int c = 0; c < 3; c++) {
                        bf16x8 kh = *(const bf16x8*)&lKh[(st * 16 + lr) * 104 + c * 32 + lq * 8];
                        bf16x8 kl = *(const bf16x8*)&lKl[(st * 16 + lr) * 104 + c * 32 + lq * 8];
                        sv = __builtin_amdgcn_mfma_f32_16x16x32_bf16(qh[rt][c], kh, sv, 0, 0, 0);
                        sv = __builtin_amdgcn_mfma_f32_16x16x32_bf16(qh[rt][c], kl, sv, 0, 0, 0);
                        sv = __builtin_amdgcn_mfma_f32_16x16x32_bf16(ql[rt][c], kh, sv, 0, 0, 0);
                    }
                    s[st] = sv;
                }
                // ---- scale + causal mask ----
                int qg0 = qrt0 + lq * 4;      // row for reg r = qg0 + r
                int c0 = k0 + lr, c1 = c0 + 16;
#pragma unroll
                for (int r = 0; r < 4; r++) {
                    s[0][r] = (c0 <= qg0 + r) ? s[0][r] * SC : -3.0e38f;
                    s[1][r] = (c1 <= qg0 + r) ? s[1][r] * SC : -3.0e38f;
                }
                // ---- online softmax (16-lane row reductions) ----
                floatx4 rm = max4(s[0], s[1]);
#pragma unroll
                for (int off = 1; off < 16; off <<= 1) rm = max4(rm, shfl_xor4(rm, off));
                floatx4 mnew = max4(mrow[rt], rm);
                floatx4 alpha = exp4(mrow[rt] - mnew);
                mrow[rt] = mnew;
                floatx4 p0 = exp4(s[0] - mnew);
                floatx4 p1 = exp4(s[1] - mnew);
                floatx4 rs = p0 + p1;
#pragma unroll
                for (int off = 1; off < 16; off <<= 1) rs = rs + shfl_xor4(rs, off);
                lsum[rt] = lsum[rt] * alpha + rs;
#pragma unroll
                for (int nt = 0; nt < 5; nt++) acc[rt][nt] *= alpha;
                // ---- P (bf16) -> wave-private LDS, D-layout -> A-layout ----
#pragma unroll
                for (int r = 0; r < 4; r++) {
                    lPw[(lq * 4 + r) * 40 + lr]      = f2bf_bits(p0[r]);
                    lPw[(lq * 4 + r) * 40 + 16 + lr] = f2bf_bits(p1[r]);
                }
                __builtin_amdgcn_s_waitcnt(0xC07F);   // lgkmcnt(0) only (intra-wave LDS RAW)
                bf16x8 pa = *(const bf16x8*)&lPw[lr * 40 + lq * 8];
                // ---- O += P V ----
#pragma unroll
                for (int nt = 0; nt < 5; nt++) {
                    bf16x8 vh = *(const bf16x8*)&lVh[(nt * 16 + lr) * 40 + lq * 8];
                    bf16x8 vl = *(const bf16x8*)&lVl[(nt * 16 + lr) * 40 + lq * 8];
                    acc[rt][nt] = __builtin_amdgcn_mfma_f32_16x16x32_bf16(pa, vh, acc[rt][nt], 0, 0, 0);
                    acc[rt][nt] = __builtin_amdgcn_mfma_f32_16x16x32_bf16(pa, vl, acc[rt][nt], 0, 0, 0);
                }
            }
        }
        __syncthreads();
    }
    // ---- epilogue: O /= l, write split-bf16 ----
#pragma unroll
    for (int rt = 0; rt < 2; rt++) {
        floatx4 inv;
#pragma unroll
        for (int r = 0; r < 4; r++) inv[r] = 1.f / lsum[rt][r];
#pragma unroll
        for (int nt = 0; nt < 5; nt++) {
#pragma unroll
            for (int r = 0; r < 4; r++) {
                float o = acc[rt][nt][r] * inv[r];
                u16 hh = f2bf_bits(o);
                u16 ll = f2bf_bits(o - bf2f(hh));
                size_t row = rowbase + qw0 + rt * 16 + lq * 4 + r;
                Oh_[row * HIDDEN + hoff + nt * 16 + lr] = hh;
                Ol_[row * HIDDEN + hoff + nt * 16 + lr] = ll;
            }
        }
    }
}

extern "C" void kernel_launch(void* const* d_in, const int* in_sizes, int n_in,
                              void* d_out, int out_size, void* d_ws, size_t ws_size,
                              hipStream_t stream) {
    const float* hidden = (const float*)d_in[0];
    const int* pos    = (const int*)d_in[2];
    const float* Wq   = (const float*)d_in[3];
    const float* Wk   = (const float*)d_in[4];
    const float* Wv   = (const float*)d_in[5];
    const float* Wo   = (const float*)d_in[6];

    const size_t NQ = (size_t)MROWS * HIDDEN;          // 10,485,760 elems
    float* ws = (float*)d_ws;
    float* Qb = ws;                                     // [0, NQ) fp32
    float* Kb = ws + NQ;                                // [NQ, 2NQ) fp32
    float* Vb = ws + 2 * NQ;                            // [2NQ, 3NQ) fp32
    u16* Ah  = (u16*)(ws + 3 * NQ);                     // NQ u16
    u16* Al  = Ah + NQ;                                 // NQ u16
    u16* WTh = Al + NQ;                                 // 2560^2 u16
    u16* WTl = WTh + (size_t)HIDDEN * HIDDEN;           // 2560^2 u16
    // region reuse (194 MB total, same footprint as round 3):
    u16* Vth = Ah;                    // after QKV GEMMs, Ah/Al free
    u16* Vtl = Al;
    u16* Qh  = (u16*)Vb;              // after vtrans, Vb free
    u16* Ql  = Qh + NQ;
    u16* Kh  = (u16*)Qb;              // after Q split, Qb free
    u16* Kl  = Kh + NQ;
    u16* Oh  = (u16*)Kb;              // after K split, Kb free
    u16* Ol  = Oh + NQ;

    dim3 blk(256);
    dim3 wgrid(HIDDEN / 64, HIDDEN / 64);
    dim3 ggrid(HIDDEN / 128, MROWS / 128);

    split_x<<<dim3(NQ / 1024), blk, 0, stream>>>(hidden, Ah, Al);
    split_wt<<<wgrid, blk, 0, stream>>>(Wq, WTh, WTl);
    gemm_bt2<<<ggrid, blk, 0, stream>>>(Ah, Al, WTh, WTl, Qb);
    split_wt<<<wgrid, blk, 0, stream>>>(Wk, WTh, WTl);
    gemm_bt2<<<ggrid, blk, 0, stream>>>(Ah, Al, WTh, WTl, Kb);
    split_wt<<<wgrid, blk, 0, stream>>>(Wv, WTh, WTl);
    gemm_bt2<<<ggrid, blk, 0, stream>>>(Ah, Al, WTh, WTl, Vb);
    rope_k<<<dim3(MROWS * NHEADS / 256), blk, 0, stream>>>(Qb, Kb, pos);
    vtrans<<<dim3(BATCH * NHEADS, SEQ / 64), blk, 0, stream>>>(Vb, Vth, Vtl);
    split_x<<<dim3(NQ / 1024), blk, 0, stream>>>(Qb, Qh, Ql);
    split_x<<<dim3(NQ / 1024), blk, 0, stream>>>(Kb, Kh, Kl);
    attn_mfma<<<dim3(BATCH * NHEADS, SEQ / QB), blk, 0, stream>>>(Qh, Ql, Kh, Kl,
                                                                  Vth, Vtl, Oh, Ol);
    split_wt<<<wgrid, blk, 0, stream>>>(Wo, WTh, WTl);
    gemm_bt2<<<ggrid, blk, 0, stream>>>(Oh, Ol, WTh, WTl, (float*)d_out);
}

// Round 2
// 1330.311 us; speedup vs baseline: 1.0728x; 1.0112x over previous
//
#include <hip/hip_runtime.h>
#include <stdint.h>

typedef unsigned short u16;
typedef __bf16 bf16x8 __attribute__((ext_vector_type(8)));
typedef float floatx4 __attribute__((ext_vector_type(4)));

#define HIDDEN 2560
#define NHEADS 32
#define HD 80
#define SEQ 2048
#define BATCH 2
#define MROWS (BATCH*SEQ)
#define QB 128

__device__ __forceinline__ float bf2f(uint32_t bits) {
    return __uint_as_float(bits << 16);
}
__device__ __forceinline__ u16 f2bf_bits(float f) {
    uint32_t x = __float_as_uint(f);
    uint32_t r = (x + 0x7fffu + ((x >> 16) & 1u)) >> 16;  // RTNE
    return (u16)r;
}
__device__ __forceinline__ floatx4 mk4(float x) {
    return (floatx4){x, x, x, x};
}
__device__ __forceinline__ floatx4 max4(floatx4 a, floatx4 b) {
    floatx4 r;
#pragma unroll
    for (int i = 0; i < 4; i++) r[i] = fmaxf(a[i], b[i]);
    return r;
}
__device__ __forceinline__ floatx4 exp4(floatx4 a) {
    floatx4 r;
#pragma unroll
    for (int i = 0; i < 4; i++) r[i] = __expf(a[i]);
    return r;
}
// DPP row_ror<N> across each 16-lane row (pure VALU cross-lane, no LDS pipe)
template <int N>
__device__ __forceinline__ floatx4 ror16_4(floatx4 v) {
    floatx4 r;
#pragma unroll
    for (int i = 0; i < 4; i++)
        r[i] = __int_as_float(__builtin_amdgcn_update_dpp(
            0, __float_as_int(v[i]), 0x120 + N, 0xF, 0xF, true));
    return r;
}
__device__ __forceinline__ floatx4 redmax16(floatx4 v) {
    v = max4(v, ror16_4<1>(v));
    v = max4(v, ror16_4<2>(v));
    v = max4(v, ror16_4<4>(v));
    v = max4(v, ror16_4<8>(v));
    return v;
}
__device__ __forceinline__ floatx4 redsum16(floatx4 v) {
    v = v + ror16_4<1>(v);
    v = v + ror16_4<2>(v);
    v = v + ror16_4<4>(v);
    v = v + ror16_4<8>(v);
    return v;
}
// async global->LDS, 16B per lane; dest is wave-uniform base + lane*16 (linear)
__device__ __forceinline__ void gload16(const u16* g, u16* l) {
    __builtin_amdgcn_global_load_lds(
        (const __attribute__((address_space(1))) uint32_t*)g,
        (__attribute__((address_space(3))) uint32_t*)l, 16, 0, 0);
}

// ---------------- split fp32 -> bf16 hi/lo, elementwise ---------------------------
__global__ __launch_bounds__(256) void split_x(const float* __restrict__ in,
                                               u16* __restrict__ hi,
                                               u16* __restrict__ lo) {
    size_t i4 = (size_t)blockIdx.x * 256 + threadIdx.x;
    float4 v = ((const float4*)in)[i4];
    float f[4] = {v.x, v.y, v.z, v.w};
    u16 h[4], l[4];
#pragma unroll
    for (int j = 0; j < 4; j++) {
        h[j] = f2bf_bits(f[j]);
        l[j] = f2bf_bits(f[j] - bf2f(h[j]));
    }
    ((uint2*)hi)[i4] = *(uint2*)h;
    ((uint2*)lo)[i4] = *(uint2*)l;
}

// ------------- transpose + split: W[k][n] fp32 -> WT hi/lo bf16 [n][k] ------------
__global__ __launch_bounds__(256) void split_wt(const float* __restrict__ in,
                                                u16* __restrict__ outh,
                                                u16* __restrict__ outl) {
    __shared__ float t[64][65];
    int k0 = blockIdx.x * 64;
    int n0 = blockIdx.y * 64;
    int tid = threadIdx.x;
    int rr = tid >> 4;
    int c4 = (tid & 15) * 4;
#pragma unroll
    for (int it = 0; it < 4; it++) {
        int row = it * 16 + rr;
        float4 v = *(const float4*)&in[(size_t)(k0 + row) * HIDDEN + n0 + c4];
        t[row][c4 + 0] = v.x; t[row][c4 + 1] = v.y;
        t[row][c4 + 2] = v.z; t[row][c4 + 3] = v.w;
    }
    __syncthreads();
#pragma unroll
    for (int it = 0; it < 4; it++) {
        int row = it * 16 + rr;
        float f[4] = { t[c4 + 0][row], t[c4 + 1][row], t[c4 + 2][row], t[c4 + 3][row] };
        u16 h[4], l[4];
#pragma unroll
        for (int j = 0; j < 4; j++) {
            h[j] = f2bf_bits(f[j]);
            l[j] = f2bf_bits(f[j] - bf2f(h[j]));
        }
        size_t o = (size_t)(n0 + row) * HIDDEN + k0 + c4;
        *(uint2*)&outh[o] = *(uint2*)h;
        *(uint2*)&outl[o] = *(uint2*)l;
    }
}

// ------- GEMM: C[M][N] = A[M][K] * Bt[N][K]^T, pre-split bf16 in, fp32 out --------
__global__ __launch_bounds__(256) void gemm_bt2(const u16* __restrict__ Ah,
                                                const u16* __restrict__ Al,
                                                const u16* __restrict__ Bh,
                                                const u16* __restrict__ Bl,
                                                float* __restrict__ C) {
    __shared__ u16 lAh[128 * 32];
    __shared__ u16 lAl[128 * 32];
    __shared__ u16 lBh[128 * 32];
    __shared__ u16 lBl[128 * 32];
    const int K = HIDDEN;
    int tid  = threadIdx.x;
    int lane = tid & 63;
    int wave = tid >> 6;
    int wr = wave >> 1, wc = wave & 1;
    int m0 = blockIdx.y * 128, n0 = blockIdx.x * 128;
    int lr = lane & 15, lq = lane >> 4;

    int srow = wave * 32 + (lane >> 2);
    int scol = ((lane & 3) ^ ((lane >> 3) & 3)) * 8;
    const u16* gAh = Ah + (size_t)(m0 + srow) * K + scol;
    const u16* gAl = Al + (size_t)(m0 + srow) * K + scol;
    const u16* gBh = Bh + (size_t)(n0 + srow) * K + scol;
    const u16* gBl = Bl + (size_t)(n0 + srow) * K + scol;
    const size_t q1 = (size_t)16 * K;
    u16* dAh = &lAh[(wave * 32) * 32];
    u16* dAl = &lAl[(wave * 32) * 32];
    u16* dBh = &lBh[(wave * 32) * 32];
    u16* dBl = &lBl[(wave * 32) * 32];

    floatx4 acc[4][4];
#pragma unroll
    for (int i = 0; i < 4; i++)
#pragma unroll
        for (int j = 0; j < 4; j++)
            acc[i][j] = mk4(0.f);

    int swz = (lr >> 1) & 3;
    int rsl = (lq ^ swz) * 8;

    for (int k0 = 0; k0 < K; k0 += 32) {
        gload16(gAh + k0, dAh);  gload16(gAh + q1 + k0, dAh + 16 * 32);
        gload16(gAl + k0, dAl);  gload16(gAl + q1 + k0, dAl + 16 * 32);
        gload16(gBh + k0, dBh);  gload16(gBh + q1 + k0, dBh + 16 * 32);
        gload16(gBl + k0, dBl);  gload16(gBl + q1 + k0, dBl + 16 * 32);
        __syncthreads();
        bf16x8 ah[4], al[4], bh[4], bl[4];
#pragma unroll
        for (int i = 0; i < 4; i++) {
            int ra = (wr * 64 + i * 16 + lr) * 32 + rsl;
            int rb = (wc * 64 + i * 16 + lr) * 32 + rsl;
            ah[i] = *(const bf16x8*)&lAh[ra];
            al[i] = *(const bf16x8*)&lAl[ra];
            bh[i] = *(const bf16x8*)&lBh[rb];
            bl[i] = *(const bf16x8*)&lBl[rb];
        }
#pragma unroll
        for (int i = 0; i < 4; i++)
#pragma unroll
            for (int j = 0; j < 4; j++) {
                acc[i][j] = __builtin_amdgcn_mfma_f32_16x16x32_bf16(ah[i], bh[j], acc[i][j], 0, 0, 0);
                acc[i][j] = __builtin_amdgcn_mfma_f32_16x16x32_bf16(ah[i], bl[j], acc[i][j], 0, 0, 0);
                acc[i][j] = __builtin_amdgcn_mfma_f32_16x16x32_bf16(al[i], bh[j], acc[i][j], 0, 0, 0);
            }
        __syncthreads();
    }
#pragma unroll
    for (int i = 0; i < 4; i++) {
        int rowb = m0 + wr * 64 + i * 16 + lq * 4;
#pragma unroll
        for (int j = 0; j < 4; j++) {
            int col = n0 + wc * 64 + j * 16 + lr;
#pragma unroll
            for (int r = 0; r < 4; r++)
                C[(size_t)(rowb + r) * HIDDEN + col] = acc[i][j][r];
        }
    }
}

// ---------------- RoPE (ROT=20 -> 10 pairs) on Q and K, in place, fp32 -----------
__global__ __launch_bounds__(256) void rope_k(float* __restrict__ Qb, float* __restrict__ Kb,
                                              const int* __restrict__ pos_ids) {
    int idx = blockIdx.x * 256 + threadIdx.x;
    int row = idx >> 5;
    int h   = idx & 31;
    float pos = (float)pos_ids[row];
    size_t base = (size_t)row * HIDDEN + h * HD;
    float* q = Qb + base;
    float* k = Kb + base;
#pragma unroll
    for (int i = 0; i < 10; i++) {
        float freq = pos * exp2f(-1.3287712379549449f * (float)i);
        float sn, cs;
        sincosf(freq, &sn, &cs);
        float q1 = q[i], q2 = q[i + 10];
        q[i]      = q1 * cs - q2 * sn;
        q[i + 10] = q2 * cs + q1 * sn;
        float k1 = k[i], k2 = k[i + 10];
        k[i]      = k1 * cs - k2 * sn;
        k[i + 10] = k2 * cs + k1 * sn;
    }
}

// ---- V transpose+split: Vb fp32 [b*S+s][2560] -> Vth/Vtl u16 [bh][d(80)][s(2048)]
__global__ __launch_bounds__(256) void vtrans(const float* __restrict__ Vb,
                                              u16* __restrict__ Vth,
                                              u16* __restrict__ Vtl) {
    __shared__ float t[64][81];
    int bh = blockIdx.x; int b = bh >> 5, h = bh & 31;
    int s0 = blockIdx.y * 64;
    int tid = threadIdx.x;
    for (int idx = tid; idx < 64 * 20; idx += 256) {
        int s = idx / 20, c = idx % 20;
        float4 v = *(const float4*)&Vb[(size_t)(b * SEQ + s0 + s) * HIDDEN + h * HD + c * 4];
        t[s][c * 4 + 0] = v.x; t[s][c * 4 + 1] = v.y;
        t[s][c * 4 + 2] = v.z; t[s][c * 4 + 3] = v.w;
    }
    __syncthreads();
    for (int idx = tid; idx < 80 * 8; idx += 256) {
        int d = idx >> 3, sc = idx & 7;
        u16 hh[8], ll[8];
#pragma unroll
        for (int j = 0; j < 8; j++) {
            float f = t[sc * 8 + j][d];
            hh[j] = f2bf_bits(f);
            ll[j] = f2bf_bits(f - bf2f(hh[j]));
        }
        size_t o = ((size_t)bh * HD + d) * SEQ + s0 + sc * 8;
        *(int4*)&Vth[o] = *(int4*)hh;
        *(int4*)&Vtl[o] = *(int4*)ll;
    }
}

// ---------------- MFMA flash attention, v2 --------------------------------------
// 128 queries/block (4 waves x 32). 32-key tiles, double-buffered, single barrier
// per tile. Staging entirely via global_load_lds (5 calls/wave: w0=Kh, w1=Kl,
// w2=Vh, w3=Vl). Layouts (per buffer, u16 offs):
//   K0h [32][64] @0      slot swizzle ^(row&7)     (cols 0..63)
//   K0l [32][64] @2048
//   K1  [64][16] @4096   rows 0..31 = Kh cols 64..79, rows 32..63 = Kl cols 64..79
//   Vh  [80][32] @5120   slot swizzle ^((row>>1)&3)
//   Vl  [80][32] @7680
// QK tail: 2 mfmas with packed A = [Qh.tail|Ql.tail] and [Ql.tail|Qh.tail].
// Softmax: DPP row_ror reductions + defer-max (THR=8).
__global__ __launch_bounds__(256) void attn_mfma(const u16* __restrict__ Qh_,
                                                 const u16* __restrict__ Ql_,
                                                 const u16* __restrict__ Kh_,
                                                 const u16* __restrict__ Kl_,
                                                 const u16* __restrict__ Vth_,
                                                 const u16* __restrict__ Vtl_,
                                                 u16* __restrict__ Oh_,
                                                 u16* __restrict__ Ol_) {
    __shared__ u16 lds[22784];          // 2*10240 tile bufs + 4*576 P = 45568 B

    int tid = threadIdx.x;
    int lane = tid & 63, w = tid >> 6;
    int lr = lane & 15, lq = lane >> 4;
    int bh = blockIdx.x; int b = bh >> 5, h = bh & 31;
    int qblk = (gridDim.y - 1) - blockIdx.y;   // long blocks dispatched first
    int q0 = qblk * QB;
    size_t rowbase = (size_t)b * SEQ;
    size_t hoff = (size_t)h * HD;
    const float SC = 0.11180339887498949f;     // 1/sqrt(80)

    // ---- stage Q (two rounds of 64 rows through buffer region) -> A-frags ----
    bf16x8 qh[2][2], ql[2][2], qta[2], qtb[2];
#pragma unroll
    for (int round = 0; round < 2; round++) {
        for (int idx = tid; idx < 1280; idx += 256) {
            int buf = idx >= 640; int e = idx - buf * 640;
            int r = e / 10, c = e % 10;
            const u16* src = (buf ? Ql_ : Qh_) +
                (rowbase + q0 + round * 64 + r) * HIDDEN + hoff + c * 8;
            *(int4*)&lds[buf * 6656 + r * 104 + c * 8] = *(const int4*)src;
        }
        __syncthreads();
        if ((w >> 1) == round) {
            int wl = w & 1;
            int tba = (lq >> 1) ? 6656 : 0;      // qta: lq<2 -> Qh else Ql
            int tbb = (lq >> 1) ? 0 : 6656;      // qtb: swapped
            int tcol = 64 + (lq & 1) * 8;
#pragma unroll
            for (int rt = 0; rt < 2; rt++) {
                int lrow = wl * 32 + rt * 16 + lr;
#pragma unroll
                for (int c = 0; c < 2; c++) {
                    qh[rt][c] = *(const bf16x8*)&lds[lrow * 104 + c * 32 + lq * 8];
                    ql[rt][c] = *(const bf16x8*)&lds[6656 + lrow * 104 + c * 32 + lq * 8];
                }
                qta[rt] = *(const bf16x8*)&lds[tba + lrow * 104 + tcol];
                qtb[rt] = *(const bf16x8*)&lds[tbb + lrow * 104 + tcol];
            }
        }
        __syncthreads();
    }

    floatx4 acc[2][5];
    floatx4 mrow[2], lsum[2];
#pragma unroll
    for (int rt = 0; rt < 2; rt++) {
        mrow[rt] = mk4(-3.0e38f);
        lsum[rt] = mk4(0.f);
#pragma unroll
        for (int nt = 0; nt < 5; nt++) acc[rt][nt] = mk4(0.f);
    }

    int ntiles = 4 * qblk + 4;
    int qw0 = q0 + w * 32;
    u16* lPw = lds + 20480 + w * 576;

    // per-lane staging address components (element units)
    int k0RowOff = (lane >> 3) * HIDDEN + (((lane & 7) ^ (lane >> 3)) * 8);
    int k1RowOff = (lane >> 1) * HIDDEN + 64 + (lane & 1) * 8;
    int vRowOff  = (lane >> 2) * SEQ + ((((lane & 3) ^ ((lane >> 3) & 3))) * 8);
    const u16* kSrc = (w & 1 ? Kl_ : Kh_) + rowbase * HIDDEN + hoff;
    const u16* vSrc = (w == 3 ? Vtl_ : Vth_) + (size_t)bh * HD * SEQ;

    auto stage = [&](int t, int bsel) {
        int k0 = t * 32;
        u16* B = lds + bsel * 10240;
        if (w < 2) {
            const u16* kb = kSrc + (size_t)k0 * HIDDEN;
            u16* d0 = B + w * 2048;
#pragma unroll
            for (int j = 0; j < 4; j++)
                gload16(kb + (size_t)j * 8 * HIDDEN + k0RowOff, d0 + j * 512);
            gload16(kb + k1RowOff, B + 4096 + w * 512);
        } else {
            const u16* vb = vSrc + k0;
            u16* d0 = B + 5120 + (w == 3 ? 2560 : 0);
#pragma unroll
            for (int j = 0; j < 5; j++)
                gload16(vb + (size_t)j * 16 * SEQ + vRowOff, d0 + j * 512);
        }
    };

    // read-side swizzle constants (thread-invariant)
    int ks0 = ((lq) ^ (lr & 7)) * 8;          // K0 c=0 slot
    int ks1 = ((4 + lq) ^ (lr & 7)) * 8;      // K0 c=1 slot
    int k1off = (lq >> 1) * 512 + (lq & 1) * 8;
    int vsl = (lq ^ ((lr >> 1) & 3)) * 8;

    stage(0, 0);

    for (int t = 0; t < ntiles; t++) {
        int k0 = t * 32;
        __syncthreads();                         // drains vmcnt(0): tile t ready
        if (t + 1 < ntiles) stage(t + 1, (t + 1) & 1);
        u16* B = lds + (t & 1) * 10240;
        if (k0 <= qw0 + 31) {
            u16* bK0h = B;
            u16* bK0l = B + 2048;
            u16* bK1  = B + 4096;
            u16* bVh  = B + 5120;
            u16* bVl  = B + 7680;
            __builtin_amdgcn_s_setprio(1);
            // hoist K fragments (shared across rt)
            bf16x8 kfh[2][2], kfl[2][2], k1f[2];
#pragma unroll
            for (int st = 0; st < 2; st++) {
                int krow = st * 16 + lr;
                kfh[st][0] = *(const bf16x8*)&bK0h[krow * 64 + ks0];
                kfh[st][1] = *(const bf16x8*)&bK0h[krow * 64 + ks1];
                kfl[st][0] = *(const bf16x8*)&bK0l[krow * 64 + ks0];
                kfl[st][1] = *(const bf16x8*)&bK0l[krow * 64 + ks1];
                k1f[st] = *(const bf16x8*)&bK1[krow * 16 + k1off];
            }
#pragma unroll
            for (int rt = 0; rt < 2; rt++) {
                int qrt0 = qw0 + rt * 16;
                if (k0 > qrt0 + 15) continue;
                // ---- S = Q K^T ----
                floatx4 s[2];
#pragma unroll
                for (int st = 0; st < 2; st++) {
                    floatx4 sv = mk4(0.f);
                    sv = __builtin_amdgcn_mfma_f32_16x16x32_bf16(qh[rt][0], kfh[st][0], sv, 0, 0, 0);
                    sv = __builtin_amdgcn_mfma_f32_16x16x32_bf16(qh[rt][0], kfl[st][0], sv, 0, 0, 0);
                    sv = __builtin_amdgcn_mfma_f32_16x16x32_bf16(ql[rt][0], kfh[st][0], sv, 0, 0, 0);
                    sv = __builtin_amdgcn_mfma_f32_16x16x32_bf16(qh[rt][1], kfh[st][1], sv, 0, 0, 0);
                    sv = __builtin_amdgcn_mfma_f32_16x16x32_bf16(qh[rt][1], kfl[st][1], sv, 0, 0, 0);
                    sv = __builtin_amdgcn_mfma_f32_16x16x32_bf16(ql[rt][1], kfh[st][1], sv, 0, 0, 0);
                    sv = __builtin_amdgcn_mfma_f32_16x16x32_bf16(qta[rt], k1f[st], sv, 0, 0, 0);
                    sv = __builtin_amdgcn_mfma_f32_16x16x32_bf16(qtb[rt], k1f[st], sv, 0, 0, 0);
                    s[st] = sv;
                }
                // ---- scale + causal mask ----
                int qg0 = qrt0 + lq * 4;
                int c0 = k0 + lr, c1 = c0 + 16;
#pragma unroll
                for (int r = 0; r < 4; r++) {
                    s[0][r] = (c0 <= qg0 + r) ? s[0][r] * SC : -3.0e38f;
                    s[1][r] = (c1 <= qg0 + r) ? s[1][r] * SC : -3.0e38f;
                }
                // ---- online softmax (DPP reductions, defer-max) ----
                floatx4 rm = redmax16(max4(s[0], s[1]));
                int small = (rm[0] <= mrow[rt][0] + 8.f) & (rm[1] <= mrow[rt][1] + 8.f) &
                            (rm[2] <= mrow[rt][2] + 8.f) & (rm[3] <= mrow[rt][3] + 8.f);
                floatx4 p0, p1;
                if (__all(small)) {
                    p0 = exp4(s[0] - mrow[rt]);
                    p1 = exp4(s[1] - mrow[rt]);
                    lsum[rt] = lsum[rt] + redsum16(p0 + p1);
                } else {
                    floatx4 mnew = max4(mrow[rt], rm);
                    floatx4 alpha = exp4(mrow[rt] - mnew);
                    mrow[rt] = mnew;
                    p0 = exp4(s[0] - mnew);
                    p1 = exp4(s[1] - mnew);
                    lsum[rt] = lsum[rt] * alpha + redsum16(p0 + p1);
#pragma unroll
                    for (int nt = 0; nt < 5; nt++) acc[rt][nt] *= alpha;
                }
                // ---- P (bf16) -> wave-private LDS, D-layout -> A-layout ----
#pragma unroll
                for (int r = 0; r < 4; r++) {
                    lPw[(lq * 4 + r) * 36 + lr]      = f2bf_bits(p0[r]);
                    lPw[(lq * 4 + r) * 36 + 16 + lr] = f2bf_bits(p1[r]);
                }
                __builtin_amdgcn_s_waitcnt(0xC07F);   // lgkmcnt(0) only (intra-wave LDS RAW)
                bf16x8 pa = *(const bf16x8*)&lPw[lr * 36 + lq * 8];
                // ---- O += P V ----
#pragma unroll
                for (int nt = 0; nt < 5; nt++) {
                    bf16x8 vh = *(const bf16x8*)&bVh[(nt * 16 + lr) * 32 + vsl];
                    bf16x8 vl = *(const bf16x8*)&bVl[(nt * 16 + lr) * 32 + vsl];
                    acc[rt][nt] = __builtin_amdgcn_mfma_f32_16x16x32_bf16(pa, vh, acc[rt][nt], 0, 0, 0);
                    acc[rt][nt] = __builtin_amdgcn_mfma_f32_16x16x32_bf16(pa, vl, acc[rt][nt], 0, 0, 0);
                }
            }
            __builtin_amdgcn_s_setprio(0);
        }
    }
    // ---- epilogue: O /= l, write split-bf16 ----
#pragma unroll
    for (int rt = 0; rt < 2; rt++) {
        floatx4 inv;
#pragma unroll
        for (int r = 0; r < 4; r++) inv[r] = 1.f / lsum[rt][r];
#pragma unroll
        for (int nt = 0; nt < 5; nt++) {
#pragma unroll
            for (int r = 0; r < 4; r++) {
                float o = acc[rt][nt][r] * inv[r];
                u16 hh = f2bf_bits(o);
                u16 ll = f2bf_bits(o - bf2f(hh));
                size_t row = rowbase + qw0 + rt * 16 + lq * 4 + r;
                Oh_[row * HIDDEN + hoff + nt * 16 + lr] = hh;
                Ol_[row * HIDDEN + hoff + nt * 16 + lr] = ll;
            }
        }
    }
}

extern "C" void kernel_launch(void* const* d_in, const int* in_sizes, int n_in,
                              void* d_out, int out_size, void* d_ws, size_t ws_size,
                              hipStream_t stream) {
    const float* hidden = (const float*)d_in[0];
    const int* pos    = (const int*)d_in[2];
    const float* Wq   = (const float*)d_in[3];
    const float* Wk   = (const float*)d_in[4];
    const float* Wv   = (const float*)d_in[5];
    const float* Wo   = (const float*)d_in[6];

    const size_t NQ = (size_t)MROWS * HIDDEN;          // 10,485,760 elems
    float* ws = (float*)d_ws;
    float* Qb = ws;                                     // [0, NQ) fp32
    float* Kb = ws + NQ;                                // [NQ, 2NQ) fp32
    float* Vb = ws + 2 * NQ;                            // [2NQ, 3NQ) fp32
    u16* Ah  = (u16*)(ws + 3 * NQ);                     // NQ u16
    u16* Al  = Ah + NQ;                                 // NQ u16
    u16* WTh = Al + NQ;                                 // 2560^2 u16
    u16* WTl = WTh + (size_t)HIDDEN * HIDDEN;           // 2560^2 u16
    u16* Vth = Ah;                    // after QKV GEMMs, Ah/Al free
    u16* Vtl = Al;
    u16* Qh  = (u16*)Vb;              // after vtrans, Vb free
    u16* Ql  = Qh + NQ;
    u16* Kh  = (u16*)Qb;              // after Q split, Qb free
    u16* Kl  = Kh + NQ;
    u16* Oh  = (u16*)Kb;              // after K split, Kb free
    u16* Ol  = Oh + NQ;

    dim3 blk(256);
    dim3 wgrid(HIDDEN / 64, HIDDEN / 64);
    dim3 ggrid(HIDDEN / 128, MROWS / 128);

    split_x<<<dim3(NQ / 1024), blk, 0, stream>>>(hidden, Ah, Al);
    split_wt<<<wgrid, blk, 0, stream>>>(Wq, WTh, WTl);
    gemm_bt2<<<ggrid, blk, 0, stream>>>(Ah, Al, WTh, WTl, Qb);
    split_wt<<<wgrid, blk, 0, stream>>>(Wk, WTh, WTl);
    gemm_bt2<<<ggrid, blk, 0, stream>>>(Ah, Al, WTh, WTl, Kb);
    split_wt<<<wgrid, blk, 0, stream>>>(Wv, WTh, WTl);
    gemm_bt2<<<ggrid, blk, 0, stream>>>(Ah, Al, WTh, WTl, Vb);
    rope_k<<<dim3(MROWS * NHEADS / 256), blk, 0, stream>>>(Qb, Kb, pos);
    vtrans<<<dim3(BATCH * NHEADS, SEQ / 64), blk, 0, stream>>>(Vb, Vth, Vtl);
    split_x<<<dim3(NQ / 1024), blk, 0, stream>>>(Qb, Qh, Ql);
    split_x<<<dim3(NQ / 1024), blk, 0, stream>>>(Kb, Kh, Kl);
    attn_mfma<<<dim3(BATCH * NHEADS, SEQ / QB), blk, 0, stream>>>(Qh, Ql, Kh, Kl,
                                                                  Vth, Vtl, Oh, Ol);
    split_wt<<<wgrid, blk, 0, stream>>>(Wo, WTh, WTl);
    gemm_bt2<<<ggrid, blk, 0, stream>>>(Oh, Ol, WTh, WTl, (float*)d_out);
}

// Round 3
// 1299.848 us; speedup vs baseline: 1.0980x; 1.0234x over previous
//
#include <hip/hip_runtime.h>
#include <stdint.h>

typedef unsigned short u16;
typedef __bf16 bf16x8 __attribute__((ext_vector_type(8)));
typedef float floatx4 __attribute__((ext_vector_type(4)));

#define HIDDEN 2560
#define NHEADS 32
#define HD 80
#define SEQ 2048
#define BATCH 2
#define MROWS (BATCH*SEQ)
#define QB 128

__device__ __forceinline__ float bf2f(uint32_t bits) {
    return __uint_as_float(bits << 16);
}
__device__ __forceinline__ u16 f2bf_bits(float f) {
    uint32_t x = __float_as_uint(f);
    uint32_t r = (x + 0x7fffu + ((x >> 16) & 1u)) >> 16;  // RTNE
    return (u16)r;
}
__device__ __forceinline__ floatx4 mk4(float x) {
    return (floatx4){x, x, x, x};
}
__device__ __forceinline__ floatx4 exp4(floatx4 a) {
    floatx4 r;
#pragma unroll
    for (int i = 0; i < 4; i++) r[i] = __expf(a[i]);
    return r;
}
// async global->LDS, 16B per lane; dest is wave-uniform base + lane*16 (linear)
__device__ __forceinline__ void gload16(const u16* g, u16* l) {
    __builtin_amdgcn_global_load_lds(
        (const __attribute__((address_space(1))) uint32_t*)g,
        (__attribute__((address_space(3))) uint32_t*)l, 16, 0, 0);
}

// ---------------- split fp32 -> bf16 hi/lo, elementwise (optional scale) ---------
__global__ __launch_bounds__(256) void split_x(const float* __restrict__ in,
                                               u16* __restrict__ hi,
                                               u16* __restrict__ lo,
                                               float scale) {
    size_t i4 = (size_t)blockIdx.x * 256 + threadIdx.x;
    float4 v = ((const float4*)in)[i4];
    float f[4] = {v.x * scale, v.y * scale, v.z * scale, v.w * scale};
    u16 h[4], l[4];
#pragma unroll
    for (int j = 0; j < 4; j++) {
        h[j] = f2bf_bits(f[j]);
        l[j] = f2bf_bits(f[j] - bf2f(h[j]));
    }
    ((uint2*)hi)[i4] = *(uint2*)h;
    ((uint2*)lo)[i4] = *(uint2*)l;
}

// ------------- transpose + split: W[k][n] fp32 -> WT hi/lo bf16 [n][k] ------------
__global__ __launch_bounds__(256) void split_wt(const float* __restrict__ in,
                                                u16* __restrict__ outh,
                                                u16* __restrict__ outl) {
    __shared__ float t[64][65];
    int k0 = blockIdx.x * 64;
    int n0 = blockIdx.y * 64;
    int tid = threadIdx.x;
    int rr = tid >> 4;
    int c4 = (tid & 15) * 4;
#pragma unroll
    for (int it = 0; it < 4; it++) {
        int row = it * 16 + rr;
        float4 v = *(const float4*)&in[(size_t)(k0 + row) * HIDDEN + n0 + c4];
        t[row][c4 + 0] = v.x; t[row][c4 + 1] = v.y;
        t[row][c4 + 2] = v.z; t[row][c4 + 3] = v.w;
    }
    __syncthreads();
#pragma unroll
    for (int it = 0; it < 4; it++) {
        int row = it * 16 + rr;
        float f[4] = { t[c4 + 0][row], t[c4 + 1][row], t[c4 + 2][row], t[c4 + 3][row] };
        u16 h[4], l[4];
#pragma unroll
        for (int j = 0; j < 4; j++) {
            h[j] = f2bf_bits(f[j]);
            l[j] = f2bf_bits(f[j] - bf2f(h[j]));
        }
        size_t o = (size_t)(n0 + row) * HIDDEN + k0 + c4;
        *(uint2*)&outh[o] = *(uint2*)h;
        *(uint2*)&outl[o] = *(uint2*)l;
    }
}

// ------- GEMM: C[M][N] = A[M][K] * Bt[N][K]^T, pre-split bf16 in, fp32 out --------
__global__ __launch_bounds__(256) void gemm_bt2(const u16* __restrict__ Ah,
                                                const u16* __restrict__ Al,
                                                const u16* __restrict__ Bh,
                                                const u16* __restrict__ Bl,
                                                float* __restrict__ C) {
    __shared__ u16 lAh[128 * 32];
    __shared__ u16 lAl[128 * 32];
    __shared__ u16 lBh[128 * 32];
    __shared__ u16 lBl[128 * 32];
    const int K = HIDDEN;
    int tid  = threadIdx.x;
    int lane = tid & 63;
    int wave = tid >> 6;
    int wr = wave >> 1, wc = wave & 1;
    int m0 = blockIdx.y * 128, n0 = blockIdx.x * 128;
    int lr = lane & 15, lq = lane >> 4;

    int srow = wave * 32 + (lane >> 2);
    int scol = ((lane & 3) ^ ((lane >> 3) & 3)) * 8;
    const u16* gAh = Ah + (size_t)(m0 + srow) * K + scol;
    const u16* gAl = Al + (size_t)(m0 + srow) * K + scol;
    const u16* gBh = Bh + (size_t)(n0 + srow) * K + scol;
    const u16* gBl = Bl + (size_t)(n0 + srow) * K + scol;
    const size_t q1 = (size_t)16 * K;
    u16* dAh = &lAh[(wave * 32) * 32];
    u16* dAl = &lAl[(wave * 32) * 32];
    u16* dBh = &lBh[(wave * 32) * 32];
    u16* dBl = &lBl[(wave * 32) * 32];

    floatx4 acc[4][4];
#pragma unroll
    for (int i = 0; i < 4; i++)
#pragma unroll
        for (int j = 0; j < 4; j++)
            acc[i][j] = mk4(0.f);

    int swz = (lr >> 1) & 3;
    int rsl = (lq ^ swz) * 8;

    for (int k0 = 0; k0 < K; k0 += 32) {
        gload16(gAh + k0, dAh);  gload16(gAh + q1 + k0, dAh + 16 * 32);
        gload16(gAl + k0, dAl);  gload16(gAl + q1 + k0, dAl + 16 * 32);
        gload16(gBh + k0, dBh);  gload16(gBh + q1 + k0, dBh + 16 * 32);
        gload16(gBl + k0, dBl);  gload16(gBl + q1 + k0, dBl + 16 * 32);
        __syncthreads();
        bf16x8 ah[4], al[4], bh[4], bl[4];
#pragma unroll
        for (int i = 0; i < 4; i++) {
            int ra = (wr * 64 + i * 16 + lr) * 32 + rsl;
            int rb = (wc * 64 + i * 16 + lr) * 32 + rsl;
            ah[i] = *(const bf16x8*)&lAh[ra];
            al[i] = *(const bf16x8*)&lAl[ra];
            bh[i] = *(const bf16x8*)&lBh[rb];
            bl[i] = *(const bf16x8*)&lBl[rb];
        }
#pragma unroll
        for (int i = 0; i < 4; i++)
#pragma unroll
            for (int j = 0; j < 4; j++) {
                acc[i][j] = __builtin_amdgcn_mfma_f32_16x16x32_bf16(ah[i], bh[j], acc[i][j], 0, 0, 0);
                acc[i][j] = __builtin_amdgcn_mfma_f32_16x16x32_bf16(ah[i], bl[j], acc[i][j], 0, 0, 0);
                acc[i][j] = __builtin_amdgcn_mfma_f32_16x16x32_bf16(al[i], bh[j], acc[i][j], 0, 0, 0);
            }
        __syncthreads();
    }
#pragma unroll
    for (int i = 0; i < 4; i++) {
        int rowb = m0 + wr * 64 + i * 16 + lq * 4;
#pragma unroll
        for (int j = 0; j < 4; j++) {
            int col = n0 + wc * 64 + j * 16 + lr;
#pragma unroll
            for (int r = 0; r < 4; r++)
                C[(size_t)(rowb + r) * HIDDEN + col] = acc[i][j][r];
        }
    }
}

// ---------------- RoPE (ROT=20 -> 10 pairs) on Q and K, in place, fp32 -----------
__global__ __launch_bounds__(256) void rope_k(float* __restrict__ Qb, float* __restrict__ Kb,
                                              const int* __restrict__ pos_ids) {
    int idx = blockIdx.x * 256 + threadIdx.x;
    int row = idx >> 5;
    int h   = idx & 31;
    float pos = (float)pos_ids[row];
    size_t base = (size_t)row * HIDDEN + h * HD;
    float* q = Qb + base;
    float* k = Kb + base;
#pragma unroll
    for (int i = 0; i < 10; i++) {
        float freq = pos * exp2f(-1.3287712379549449f * (float)i);
        float sn, cs;
        sincosf(freq, &sn, &cs);
        float q1 = q[i], q2 = q[i + 10];
        q[i]      = q1 * cs - q2 * sn;
        q[i + 10] = q2 * cs + q1 * sn;
        float k1 = k[i], k2 = k[i + 10];
        k[i]      = k1 * cs - k2 * sn;
        k[i + 10] = k2 * cs + k1 * sn;
    }
}

// ---- V transpose+split: Vb fp32 -> Vth/Vtl u16 [bh][d(80)][key*(2048)]
// key* layout: within each 32-key tile, col 8a+4h+j holds key 16h+4a+j
// (so the PV A-fragment's k-slot order lq*8+{0..7} = keys {4lq..4lq+3, 16+4lq..+3}
//  matches the lane-local p-values after swapped QK^T — no P shuffle needed).
__global__ __launch_bounds__(256) void vtrans(const float* __restrict__ Vb,
                                              u16* __restrict__ Vth,
                                              u16* __restrict__ Vtl) {
    __shared__ float t[64][81];
    int bh = blockIdx.x; int b = bh >> 5, h = bh & 31;
    int s0 = blockIdx.y * 64;
    int tid = threadIdx.x;
    for (int idx = tid; idx < 64 * 20; idx += 256) {
        int s = idx / 20, c = idx % 20;
        float4 v = *(const float4*)&Vb[(size_t)(b * SEQ + s0 + s) * HIDDEN + h * HD + c * 4];
        t[s][c * 4 + 0] = v.x; t[s][c * 4 + 1] = v.y;
        t[s][c * 4 + 2] = v.z; t[s][c * 4 + 3] = v.w;
    }
    __syncthreads();
    for (int idx = tid; idx < 80 * 16; idx += 256) {   // 4-key chunks
        int d = idx >> 4, ch = idx & 15;
        int t2 = ch >> 3, e = ch & 7, a = e >> 1, h2 = e & 1;
        int srck = t2 * 32 + 16 * h2 + 4 * a;
        int dstc = t2 * 32 + 8 * a + 4 * h2;
        u16 hh[4], ll[4];
#pragma unroll
        for (int j = 0; j < 4; j++) {
            float f = t[srck + j][d];
            hh[j] = f2bf_bits(f);
            ll[j] = f2bf_bits(f - bf2f(hh[j]));
        }
        size_t o = ((size_t)bh * HD + d) * SEQ + s0 + dstc;
        *(uint2*)&Vth[o] = *(uint2*)hh;
        *(uint2*)&Vtl[o] = *(uint2*)ll;
    }
}

// ---------------- MFMA flash attention, v3 (swapped QK^T, register softmax) ------
// 128 queries/block (4 waves x 32). 32-key tiles, double-buffered, single barrier
// per tile, staging via global_load_lds (w0=Kh, w1=Kl, w2=Vh, w3=Vl; 5 each).
// S^T = mfma(K, Q): lane holds q = lane&15, keys {4lq+r, 16+4lq+r} per subtile.
// Softmax per-lane scalar + 2 shfl_xor; P packed to bf16 in-register (key-
// interleaved V layout makes it the PV A-fragment directly). No P LDS.
// Q pre-scaled by 1/sqrt(HD) at split time.
__global__ __launch_bounds__(256, 4) void attn_mfma(const u16* __restrict__ Qh_,
                                                 const u16* __restrict__ Ql_,
                                                 const u16* __restrict__ Kh_,
                                                 const u16* __restrict__ Kl_,
                                                 const u16* __restrict__ Vth_,
                                                 const u16* __restrict__ Vtl_,
                                                 u16* __restrict__ Oh_,
                                                 u16* __restrict__ Ol_) {
    __shared__ u16 lds[20480];          // 2 x 10240 u16 tile buffers = 40960 B

    int tid = threadIdx.x;
    int lane = tid & 63, w = tid >> 6;
    int lr = lane & 15, lq = lane >> 4;
    int bh = blockIdx.x; int b = bh >> 5, h = bh & 31;
    int qblk = (gridDim.y - 1) - blockIdx.y;   // long blocks dispatched first
    int q0 = qblk * QB;
    size_t rowbase = (size_t)b * SEQ;
    size_t hoff = (size_t)h * HD;

    // ---- stage Q (two rounds of 64 rows through buffer region) -> B-frags ----
    bf16x8 qh[2][2], ql[2][2], qta[2];
#pragma unroll
    for (int round = 0; round < 2; round++) {
        for (int idx = tid; idx < 1280; idx += 256) {
            int buf = idx >= 640; int e = idx - buf * 640;
            int r = e / 10, c = e % 10;
            const u16* src = (buf ? Ql_ : Qh_) +
                (rowbase + q0 + round * 64 + r) * HIDDEN + hoff + c * 8;
            *(int4*)&lds[buf * 6656 + r * 104 + c * 8] = *(const int4*)src;
        }
        __syncthreads();
        if ((w >> 1) == round) {
            int wl = w & 1;
            int tba = (lq >> 1) ? 6656 : 0;      // qta: lq<2 -> Qh else Ql
            int tcol = 64 + (lq & 1) * 8;
#pragma unroll
            for (int rt = 0; rt < 2; rt++) {
                int lrow = wl * 32 + rt * 16 + lr;
#pragma unroll
                for (int c = 0; c < 2; c++) {
                    qh[rt][c] = *(const bf16x8*)&lds[lrow * 104 + c * 32 + lq * 8];
                    ql[rt][c] = *(const bf16x8*)&lds[6656 + lrow * 104 + c * 32 + lq * 8];
                }
                qta[rt] = *(const bf16x8*)&lds[tba + lrow * 104 + tcol];
            }
        }
        __syncthreads();
    }

    floatx4 acc[2][5];
    float mrow[2], lsum[2];
#pragma unroll
    for (int rt = 0; rt < 2; rt++) {
        mrow[rt] = -3.0e38f;
        lsum[rt] = 0.f;
#pragma unroll
        for (int nt = 0; nt < 5; nt++) acc[rt][nt] = mk4(0.f);
    }

    int ntiles = 4 * qblk + 4;
    int qw0 = q0 + w * 32;

    // per-lane staging address components (element units)
    int k0RowOff = (lane >> 3) * HIDDEN + (((lane & 7) ^ (lane >> 3)) * 8);
    int k1RowOff = (lane >> 1) * HIDDEN + 64 + (lane & 1) * 8;
    int vRowOff  = (lane >> 2) * SEQ + ((((lane & 3) ^ ((lane >> 3) & 3))) * 8);
    const u16* kSrc = (w & 1 ? Kl_ : Kh_) + rowbase * HIDDEN + hoff;
    const u16* vSrc = (w == 3 ? Vtl_ : Vth_) + (size_t)bh * HD * SEQ;

    auto stage = [&](int t, int bsel) {
        int k0 = t * 32;
        u16* B = lds + bsel * 10240;
        if (w < 2) {
            const u16* kb = kSrc + (size_t)k0 * HIDDEN;
            u16* d0 = B + w * 2048;
#pragma unroll
            for (int j = 0; j < 4; j++)
                gload16(kb + (size_t)j * 8 * HIDDEN + k0RowOff, d0 + j * 512);
            gload16(kb + k1RowOff, B + 4096 + w * 512);
        } else {
            const u16* vb = vSrc + k0;
            u16* d0 = B + 5120 + (w == 3 ? 2560 : 0);
#pragma unroll
            for (int j = 0; j < 5; j++)
                gload16(vb + (size_t)j * 16 * SEQ + vRowOff, d0 + j * 512);
        }
    };

    // read-side swizzle constants (thread-invariant)
    int ks0 = ((lq) ^ (lr & 7)) * 8;          // K0 c=0 slot
    int ks1 = ((4 + lq) ^ (lr & 7)) * 8;      // K0 c=1 slot
    int k1off  = (lq >> 1) * 512 + (lq & 1) * 8;          // [Kh|Kl] variant
    int k1offb = ((lq >> 1) ^ 1) * 512 + (lq & 1) * 8;    // [Kl|Kh] variant
    int vsl = (lq ^ ((lr >> 1) & 3)) * 8;

    stage(0, 0);

    for (int t = 0; t < ntiles; t++) {
        int k0 = t * 32;
        __syncthreads();                         // drains vmcnt(0): tile t ready
        if (t + 1 < ntiles) stage(t + 1, (t + 1) & 1);
        u16* B = lds + (t & 1) * 10240;
        if (k0 <= qw0 + 31) {
            u16* bK0h = B;
            u16* bK0l = B + 2048;
            u16* bK1  = B + 4096;
            u16* bVh  = B + 5120;
            u16* bVl  = B + 7680;
            __builtin_amdgcn_s_setprio(1);
#pragma unroll
            for (int rt = 0; rt < 2; rt++) {
                int qrt0 = qw0 + rt * 16;
                if (k0 > qrt0 + 15) continue;
                // ---- S^T = K Q^T (A=K frag, B=Q frag) ----
                floatx4 s[2];
#pragma unroll
                for (int st = 0; st < 2; st++) {
                    int krow = st * 16 + lr;
                    bf16x8 kh0 = *(const bf16x8*)&bK0h[krow * 64 + ks0];
                    bf16x8 kh1 = *(const bf16x8*)&bK0h[krow * 64 + ks1];
                    bf16x8 kl0 = *(const bf16x8*)&bK0l[krow * 64 + ks0];
                    bf16x8 kl1 = *(const bf16x8*)&bK0l[krow * 64 + ks1];
                    bf16x8 k1f  = *(const bf16x8*)&bK1[krow * 16 + k1off];
                    bf16x8 k1fb = *(const bf16x8*)&bK1[krow * 16 + k1offb];
                    floatx4 sv = mk4(0.f);
                    sv = __builtin_amdgcn_mfma_f32_16x16x32_bf16(kh0, qh[rt][0], sv, 0, 0, 0);
                    sv = __builtin_amdgcn_mfma_f32_16x16x32_bf16(kl0, qh[rt][0], sv, 0, 0, 0);
                    sv = __builtin_amdgcn_mfma_f32_16x16x32_bf16(kh0, ql[rt][0], sv, 0, 0, 0);
                    sv = __builtin_amdgcn_mfma_f32_16x16x32_bf16(kh1, qh[rt][1], sv, 0, 0, 0);
                    sv = __builtin_amdgcn_mfma_f32_16x16x32_bf16(kl1, qh[rt][1], sv, 0, 0, 0);
                    sv = __builtin_amdgcn_mfma_f32_16x16x32_bf16(kh1, ql[rt][1], sv, 0, 0, 0);
                    sv = __builtin_amdgcn_mfma_f32_16x16x32_bf16(k1f,  qta[rt], sv, 0, 0, 0);
                    sv = __builtin_amdgcn_mfma_f32_16x16x32_bf16(k1fb, qta[rt], sv, 0, 0, 0);
                    s[st] = sv;
                }
                // ---- causal mask (lane q = qrt0+lr; keys k0+st*16+lq*4+r) ----
                if (k0 + 31 > qrt0) {
                    int qmy = qrt0 + lr - k0 - lq * 4;   // key_local = st*16+r
#pragma unroll
                    for (int r = 0; r < 4; r++) {
                        s[0][r] = (r <= qmy)      ? s[0][r] : -3.0e38f;
                        s[1][r] = (16 + r <= qmy) ? s[1][r] : -3.0e38f;
                    }
                }
                // ---- online softmax (per-lane scalar, 4-lane column group) ----
                float rm = fmaxf(fmaxf(fmaxf(s[0][0], s[0][1]), fmaxf(s[0][2], s[0][3])),
                                 fmaxf(fmaxf(s[1][0], s[1][1]), fmaxf(s[1][2], s[1][3])));
                rm = fmaxf(rm, __shfl_xor(rm, 16));
                rm = fmaxf(rm, __shfl_xor(rm, 32));
                int need = rm > mrow[rt] + 8.f;
                if (__any(need)) {                 // rescale path (rare: defer-max)
                    float mnew = fmaxf(mrow[rt], rm);
                    float alpha = __expf(mrow[rt] - mnew);
                    mrow[rt] = mnew;
                    lsum[rt] *= alpha;
                    float at[4];
#pragma unroll
                    for (int r = 0; r < 4; r++) at[r] = __shfl(alpha, lq * 4 + r);
#pragma unroll
                    for (int nt = 0; nt < 5; nt++)
#pragma unroll
                        for (int r = 0; r < 4; r++) acc[rt][nt][r] *= at[r];
                }
                float m = mrow[rt];
                floatx4 p0 = exp4(s[0] - mk4(m));
                floatx4 p1 = exp4(s[1] - mk4(m));
                floatx4 ps = p0 + p1;
                float rs = ps[0] + ps[1] + ps[2] + ps[3];
                rs += __shfl_xor(rs, 16);
                rs += __shfl_xor(rs, 32);
                lsum[rt] += rs;
                // ---- pack P in-register (matches key-interleaved V layout) ----
                bf16x8 pa;
                pa[0] = (__bf16)p0[0]; pa[1] = (__bf16)p0[1];
                pa[2] = (__bf16)p0[2]; pa[3] = (__bf16)p0[3];
                pa[4] = (__bf16)p1[0]; pa[5] = (__bf16)p1[1];
                pa[6] = (__bf16)p1[2]; pa[7] = (__bf16)p1[3];
                // ---- O += P V ----
#pragma unroll
                for (int nt = 0; nt < 5; nt++) {
                    bf16x8 vh = *(const bf16x8*)&bVh[(nt * 16 + lr) * 32 + vsl];
                    bf16x8 vl = *(const bf16x8*)&bVl[(nt * 16 + lr) * 32 + vsl];
                    acc[rt][nt] = __builtin_amdgcn_mfma_f32_16x16x32_bf16(pa, vh, acc[rt][nt], 0, 0, 0);
                    acc[rt][nt] = __builtin_amdgcn_mfma_f32_16x16x32_bf16(pa, vl, acc[rt][nt], 0, 0, 0);
                }
            }
            __builtin_amdgcn_s_setprio(0);
        }
    }
    // ---- epilogue: O /= l, write split-bf16 ----
#pragma unroll
    for (int rt = 0; rt < 2; rt++) {
        float il = 1.f / lsum[rt];
        float inv[4];
#pragma unroll
        for (int r = 0; r < 4; r++) inv[r] = __shfl(il, lq * 4 + r);
#pragma unroll
        for (int nt = 0; nt < 5; nt++) {
#pragma unroll
            for (int r = 0; r < 4; r++) {
                float o = acc[rt][nt][r] * inv[r];
                u16 hh = f2bf_bits(o);
                u16 ll = f2bf_bits(o - bf2f(hh));
                size_t row = rowbase + qw0 + rt * 16 + lq * 4 + r;
                Oh_[row * HIDDEN + hoff + nt * 16 + lr] = hh;
                Ol_[row * HIDDEN + hoff + nt * 16 + lr] = ll;
            }
        }
    }
}

extern "C" void kernel_launch(void* const* d_in, const int* in_sizes, int n_in,
                              void* d_out, int out_size, void* d_ws, size_t ws_size,
                              hipStream_t stream) {
    const float* hidden = (const float*)d_in[0];
    const int* pos    = (const int*)d_in[2];
    const float* Wq   = (const float*)d_in[3];
    const float* Wk   = (const float*)d_in[4];
    const float* Wv   = (const float*)d_in[5];
    const float* Wo   = (const float*)d_in[6];

    const size_t NQ = (size_t)MROWS * HIDDEN;          // 10,485,760 elems
    float* ws = (float*)d_ws;
    float* Qb = ws;                                     // [0, NQ) fp32
    float* Kb = ws + NQ;                                // [NQ, 2NQ) fp32
    float* Vb = ws + 2 * NQ;                            // [2NQ, 3NQ) fp32
    u16* Ah  = (u16*)(ws + 3 * NQ);                     // NQ u16
    u16* Al  = Ah + NQ;                                 // NQ u16
    u16* WTh = Al + NQ;                                 // 2560^2 u16
    u16* WTl = WTh + (size_t)HIDDEN * HIDDEN;           // 2560^2 u16
    u16* Vth = Ah;                    // after QKV GEMMs, Ah/Al free
    u16* Vtl = Al;
    u16* Qh  = (u16*)Vb;              // after vtrans, Vb free
    u16* Ql  = Qh + NQ;
    u16* Kh  = (u16*)Qb;              // after Q split, Qb free
    u16* Kl  = Kh + NQ;
    u16* Oh  = (u16*)Kb;              // after K split, Kb free
    u16* Ol  = Oh + NQ;

    const float SC = 0.11180339887498949f;              // 1/sqrt(80)

    dim3 blk(256);
    dim3 wgrid(HIDDEN / 64, HIDDEN / 64);
    dim3 ggrid(HIDDEN / 128, MROWS / 128);

    split_x<<<dim3(NQ / 1024), blk, 0, stream>>>(hidden, Ah, Al, 1.f);
    split_wt<<<wgrid, blk, 0, stream>>>(Wq, WTh, WTl);
    gemm_bt2<<<ggrid, blk, 0, stream>>>(Ah, Al, WTh, WTl, Qb);
    split_wt<<<wgrid, blk, 0, stream>>>(Wk, WTh, WTl);
    gemm_bt2<<<ggrid, blk, 0, stream>>>(Ah, Al, WTh, WTl, Kb);
    split_wt<<<wgrid, blk, 0, stream>>>(Wv, WTh, WTl);
    gemm_bt2<<<ggrid, blk, 0, stream>>>(Ah, Al, WTh, WTl, Vb);
    rope_k<<<dim3(MROWS * NHEADS / 256), blk, 0, stream>>>(Qb, Kb, pos);
    vtrans<<<dim3(BATCH * NHEADS, SEQ / 64), blk, 0, stream>>>(Vb, Vth, Vtl);
    split_x<<<dim3(NQ / 1024), blk, 0, stream>>>(Qb, Qh, Ql, SC);
    split_x<<<dim3(NQ / 1024), blk, 0, stream>>>(Kb, Kh, Kl, 1.f);
    attn_mfma<<<dim3(BATCH * NHEADS, SEQ / QB), blk, 0, stream>>>(Qh, Ql, Kh, Kl,
                                                                  Vth, Vtl, Oh, Ol);
    split_wt<<<wgrid, blk, 0, stream>>>(Wo, WTh, WTl);
    gemm_bt2<<<ggrid, blk, 0, stream>>>(Oh, Ol, WTh, WTl, (float*)d_out);
}

// Round 4
// 1173.513 us; speedup vs baseline: 1.2162x; 1.1077x over previous
//
#include <hip/hip_runtime.h>
#include <stdint.h>

typedef unsigned short u16;
typedef __bf16 bf16x8 __attribute__((ext_vector_type(8)));
typedef float floatx4 __attribute__((ext_vector_type(4)));

#define HIDDEN 2560
#define NHEADS 32
#define HD 80
#define SEQ 2048
#define BATCH 2
#define MROWS (BATCH*SEQ)
#define QB 64

__device__ __forceinline__ float bf2f(uint32_t bits) {
    return __uint_as_float(bits << 16);
}
__device__ __forceinline__ u16 f2bf_bits(float f) {
    uint32_t x = __float_as_uint(f);
    uint32_t r = (x + 0x7fffu + ((x >> 16) & 1u)) >> 16;  // RTNE
    return (u16)r;
}
__device__ __forceinline__ floatx4 mk4(float x) {
    return (floatx4){x, x, x, x};
}
__device__ __forceinline__ floatx4 exp4(floatx4 a) {
    floatx4 r;
#pragma unroll
    for (int i = 0; i < 4; i++) r[i] = __expf(a[i]);
    return r;
}
// async global->LDS, 16B per lane; dest is wave-uniform base + lane*16 (linear)
__device__ __forceinline__ void gload16(const u16* g, u16* l) {
    __builtin_amdgcn_global_load_lds(
        (const __attribute__((address_space(1))) uint32_t*)g,
        (__attribute__((address_space(3))) uint32_t*)l, 16, 0, 0);
}

// ---------------- split fp32 -> bf16 hi/lo, elementwise (optional scale) ---------
__global__ __launch_bounds__(256) void split_x(const float* __restrict__ in,
                                               u16* __restrict__ hi,
                                               u16* __restrict__ lo,
                                               float scale) {
    size_t i4 = (size_t)blockIdx.x * 256 + threadIdx.x;
    float4 v = ((const float4*)in)[i4];
    float f[4] = {v.x * scale, v.y * scale, v.z * scale, v.w * scale};
    u16 h[4], l[4];
#pragma unroll
    for (int j = 0; j < 4; j++) {
        h[j] = f2bf_bits(f[j]);
        l[j] = f2bf_bits(f[j] - bf2f(h[j]));
    }
    ((uint2*)hi)[i4] = *(uint2*)h;
    ((uint2*)lo)[i4] = *(uint2*)l;
}

// ------------- transpose + split: W[k][n] fp32 -> WT hi/lo bf16 [n][k] ------------
__global__ __launch_bounds__(256) void split_wt(const float* __restrict__ in,
                                                u16* __restrict__ outh,
                                                u16* __restrict__ outl) {
    __shared__ float t[64][65];
    int k0 = blockIdx.x * 64;
    int n0 = blockIdx.y * 64;
    int tid = threadIdx.x;
    int rr = tid >> 4;
    int c4 = (tid & 15) * 4;
#pragma unroll
    for (int it = 0; it < 4; it++) {
        int row = it * 16 + rr;
        float4 v = *(const float4*)&in[(size_t)(k0 + row) * HIDDEN + n0 + c4];
        t[row][c4 + 0] = v.x; t[row][c4 + 1] = v.y;
        t[row][c4 + 2] = v.z; t[row][c4 + 3] = v.w;
    }
    __syncthreads();
#pragma unroll
    for (int it = 0; it < 4; it++) {
        int row = it * 16 + rr;
        float f[4] = { t[c4 + 0][row], t[c4 + 1][row], t[c4 + 2][row], t[c4 + 3][row] };
        u16 h[4], l[4];
#pragma unroll
        for (int j = 0; j < 4; j++) {
            h[j] = f2bf_bits(f[j]);
            l[j] = f2bf_bits(f[j] - bf2f(h[j]));
        }
        size_t o = (size_t)(n0 + row) * HIDDEN + k0 + c4;
        *(uint2*)&outh[o] = *(uint2*)h;
        *(uint2*)&outl[o] = *(uint2*)l;
    }
}

// ------- GEMM: C[M][N] = A[M][K] * Bt[N][K]^T, pre-split bf16 in, fp32 out --------
__global__ __launch_bounds__(256) void gemm_bt2(const u16* __restrict__ Ah,
                                                const u16* __restrict__ Al,
                                                const u16* __restrict__ Bh,
                                                const u16* __restrict__ Bl,
                                                float* __restrict__ C) {
    __shared__ u16 lAh[128 * 32];
    __shared__ u16 lAl[128 * 32];
    __shared__ u16 lBh[128 * 32];
    __shared__ u16 lBl[128 * 32];
    const int K = HIDDEN;
    int tid  = threadIdx.x;
    int lane = tid & 63;
    int wave = tid >> 6;
    int wr = wave >> 1, wc = wave & 1;
    int m0 = blockIdx.y * 128, n0 = blockIdx.x * 128;
    int lr = lane & 15, lq = lane >> 4;

    int srow = wave * 32 + (lane >> 2);
    int scol = ((lane & 3) ^ ((lane >> 3) & 3)) * 8;
    const u16* gAh = Ah + (size_t)(m0 + srow) * K + scol;
    const u16* gAl = Al + (size_t)(m0 + srow) * K + scol;
    const u16* gBh = Bh + (size_t)(n0 + srow) * K + scol;
    const u16* gBl = Bl + (size_t)(n0 + srow) * K + scol;
    const size_t q1 = (size_t)16 * K;
    u16* dAh = &lAh[(wave * 32) * 32];
    u16* dAl = &lAl[(wave * 32) * 32];
    u16* dBh = &lBh[(wave * 32) * 32];
    u16* dBl = &lBl[(wave * 32) * 32];

    floatx4 acc[4][4];
#pragma unroll
    for (int i = 0; i < 4; i++)
#pragma unroll
        for (int j = 0; j < 4; j++)
            acc[i][j] = mk4(0.f);

    int swz = (lr >> 1) & 3;
    int rsl = (lq ^ swz) * 8;

    for (int k0 = 0; k0 < K; k0 += 32) {
        gload16(gAh + k0, dAh);  gload16(gAh + q1 + k0, dAh + 16 * 32);
        gload16(gAl + k0, dAl);  gload16(gAl + q1 + k0, dAl + 16 * 32);
        gload16(gBh + k0, dBh);  gload16(gBh + q1 + k0, dBh + 16 * 32);
        gload16(gBl + k0, dBl);  gload16(gBl + q1 + k0, dBl + 16 * 32);
        __syncthreads();
        bf16x8 ah[4], al[4], bh[4], bl[4];
#pragma unroll
        for (int i = 0; i < 4; i++) {
            int ra = (wr * 64 + i * 16 + lr) * 32 + rsl;
            int rb = (wc * 64 + i * 16 + lr) * 32 + rsl;
            ah[i] = *(const bf16x8*)&lAh[ra];
            al[i] = *(const bf16x8*)&lAl[ra];
            bh[i] = *(const bf16x8*)&lBh[rb];
            bl[i] = *(const bf16x8*)&lBl[rb];
        }
#pragma unroll
        for (int i = 0; i < 4; i++)
#pragma unroll
            for (int j = 0; j < 4; j++) {
                acc[i][j] = __builtin_amdgcn_mfma_f32_16x16x32_bf16(ah[i], bh[j], acc[i][j], 0, 0, 0);
                acc[i][j] = __builtin_amdgcn_mfma_f32_16x16x32_bf16(ah[i], bl[j], acc[i][j], 0, 0, 0);
                acc[i][j] = __builtin_amdgcn_mfma_f32_16x16x32_bf16(al[i], bh[j], acc[i][j], 0, 0, 0);
            }
        __syncthreads();
    }
#pragma unroll
    for (int i = 0; i < 4; i++) {
        int rowb = m0 + wr * 64 + i * 16 + lq * 4;
#pragma unroll
        for (int j = 0; j < 4; j++) {
            int col = n0 + wc * 64 + j * 16 + lr;
#pragma unroll
            for (int r = 0; r < 4; r++)
                C[(size_t)(rowb + r) * HIDDEN + col] = acc[i][j][r];
        }
    }
}

// ---------------- RoPE (ROT=20 -> 10 pairs) on Q and K, in place, fp32 -----------
__global__ __launch_bounds__(256) void rope_k(float* __restrict__ Qb, float* __restrict__ Kb,
                                              const int* __restrict__ pos_ids) {
    int idx = blockIdx.x * 256 + threadIdx.x;
    int row = idx >> 5;
    int h   = idx & 31;
    float pos = (float)pos_ids[row];
    size_t base = (size_t)row * HIDDEN + h * HD;
    float* q = Qb + base;
    float* k = Kb + base;
#pragma unroll
    for (int i = 0; i < 10; i++) {
        float freq = pos * exp2f(-1.3287712379549449f * (float)i);
        float sn, cs;
        sincosf(freq, &sn, &cs);
        float q1 = q[i], q2 = q[i + 10];
        q[i]      = q1 * cs - q2 * sn;
        q[i + 10] = q2 * cs + q1 * sn;
        float k1 = k[i], k2 = k[i + 10];
        k[i]      = k1 * cs - k2 * sn;
        k[i + 10] = k2 * cs + k1 * sn;
    }
}

// ---- V transpose+split: Vb fp32 -> Vth/Vtl u16 [bh][d(80)][key*(2048)]
// key* layout: within each 32-key tile, col 8a+4h+j holds key 16h+4a+j
// (so the PV A-fragment's k-slot order lq*8+{0..7} = keys {4lq..4lq+3, 16+4lq..+3}
//  matches the lane-local p-values after swapped QK^T — no P shuffle needed).
__global__ __launch_bounds__(256) void vtrans(const float* __restrict__ Vb,
                                              u16* __restrict__ Vth,
                                              u16* __restrict__ Vtl) {
    __shared__ float t[64][81];
    int bh = blockIdx.x; int b = bh >> 5, h = bh & 31;
    int s0 = blockIdx.y * 64;
    int tid = threadIdx.x;
    for (int idx = tid; idx < 64 * 20; idx += 256) {
        int s = idx / 20, c = idx % 20;
        float4 v = *(const float4*)&Vb[(size_t)(b * SEQ + s0 + s) * HIDDEN + h * HD + c * 4];
        t[s][c * 4 + 0] = v.x; t[s][c * 4 + 1] = v.y;
        t[s][c * 4 + 2] = v.z; t[s][c * 4 + 3] = v.w;
    }
    __syncthreads();
    for (int idx = tid; idx < 80 * 16; idx += 256) {   // 4-key chunks
        int d = idx >> 4, ch = idx & 15;
        int t2 = ch >> 3, e = ch & 7, a = e >> 1, h2 = e & 1;
        int srck = t2 * 32 + 16 * h2 + 4 * a;
        int dstc = t2 * 32 + 8 * a + 4 * h2;
        u16 hh[4], ll[4];
#pragma unroll
        for (int j = 0; j < 4; j++) {
            float f = t[srck + j][d];
            hh[j] = f2bf_bits(f);
            ll[j] = f2bf_bits(f - bf2f(hh[j]));
        }
        size_t o = ((size_t)bh * HD + d) * SEQ + s0 + dstc;
        *(uint2*)&Vth[o] = *(uint2*)hh;
        *(uint2*)&Vtl[o] = *(uint2*)ll;
    }
}

// ---------------- MFMA flash attention, v4 (QB=64: 4 waves x 16 queries) ---------
// 64 queries/block; wave w owns queries [q0+16w, q0+16w+16). 32-key tiles,
// double-buffered, single barrier per tile, staging via global_load_lds
// (w0=Kh, w1=Kl, w2=Vh, w3=Vl; 5 calls each). S^T = mfma(K, Q): lane holds
// q = lane&15, keys {lq*4+r, 16+lq*4+r}. Softmax per-lane scalar + 2 shfl_xor;
// P packed to bf16 in-register (key-interleaved V). Q pre-scaled by 1/sqrt(HD).
// Register budget: acc 20 + Q frags 20 + K temps ~24 + addr ~15 ≈ 105 < 128,
// so __launch_bounds__(256,4) holds without spill; LDS 40960 B -> 4 blocks/CU.
__global__ __launch_bounds__(256, 4) void attn_mfma(const u16* __restrict__ Qh_,
                                                 const u16* __restrict__ Ql_,
                                                 const u16* __restrict__ Kh_,
                                                 const u16* __restrict__ Kl_,
                                                 const u16* __restrict__ Vth_,
                                                 const u16* __restrict__ Vtl_,
                                                 u16* __restrict__ Oh_,
                                                 u16* __restrict__ Ol_) {
    __shared__ u16 lds[20480];          // 2 x 10240 u16 tile buffers = 40960 B

    int tid = threadIdx.x;
    int lane = tid & 63, w = tid >> 6;
    int lr = lane & 15, lq = lane >> 4;
    int bh = blockIdx.x; int b = bh >> 5, h = bh & 31;
    int qblk = (gridDim.y - 1) - blockIdx.y;   // long blocks dispatched first
    int q0 = qblk * QB;
    size_t rowbase = (size_t)b * SEQ;
    size_t hoff = (size_t)h * HD;

    // ---- stage Q (64 rows, hi @0 / lo @6656, pitch 104) -> B-frags ----
    bf16x8 qh[2], ql[2], qta;
    for (int idx = tid; idx < 1280; idx += 256) {
        int buf = idx >= 640; int e = idx - buf * 640;
        int r = e / 10, c = e % 10;
        const u16* src = (buf ? Ql_ : Qh_) +
            (rowbase + q0 + r) * HIDDEN + hoff + c * 8;
        *(int4*)&lds[buf * 6656 + r * 104 + c * 8] = *(const int4*)src;
    }
    __syncthreads();
    {
        int tba = (lq >> 1) ? 6656 : 0;      // qta: lq<2 -> Qh else Ql
        int tcol = 64 + (lq & 1) * 8;
        int lrow = w * 16 + lr;
#pragma unroll
        for (int c = 0; c < 2; c++) {
            qh[c] = *(const bf16x8*)&lds[lrow * 104 + c * 32 + lq * 8];
            ql[c] = *(const bf16x8*)&lds[6656 + lrow * 104 + c * 32 + lq * 8];
        }
        qta = *(const bf16x8*)&lds[tba + lrow * 104 + tcol];
    }
    __syncthreads();

    floatx4 acc[5];
    float mrow = -3.0e38f, lsum = 0.f;
#pragma unroll
    for (int nt = 0; nt < 5; nt++) acc[nt] = mk4(0.f);

    int ntiles = 2 * qblk + 2;
    int qw0 = q0 + w * 16;

    // per-lane staging address components (element units)
    int k0RowOff = (lane >> 3) * HIDDEN + (((lane & 7) ^ (lane >> 3)) * 8);
    int k1RowOff = (lane >> 1) * HIDDEN + 64 + (lane & 1) * 8;
    int vRowOff  = (lane >> 2) * SEQ + ((((lane & 3) ^ ((lane >> 3) & 3))) * 8);
    const u16* kSrc = (w & 1 ? Kl_ : Kh_) + rowbase * HIDDEN + hoff;
    const u16* vSrc = (w == 3 ? Vtl_ : Vth_) + (size_t)bh * HD * SEQ;

    auto stage = [&](int t, int bsel) {
        int k0 = t * 32;
        u16* B = lds + bsel * 10240;
        if (w < 2) {
            const u16* kb = kSrc + (size_t)k0 * HIDDEN;
            u16* d0 = B + w * 2048;
#pragma unroll
            for (int j = 0; j < 4; j++)
                gload16(kb + (size_t)j * 8 * HIDDEN + k0RowOff, d0 + j * 512);
            gload16(kb + k1RowOff, B + 4096 + w * 512);
        } else {
            const u16* vb = vSrc + k0;
            u16* d0 = B + 5120 + (w == 3 ? 2560 : 0);
#pragma unroll
            for (int j = 0; j < 5; j++)
                gload16(vb + (size_t)j * 16 * SEQ + vRowOff, d0 + j * 512);
        }
    };

    // read-side swizzle constants (thread-invariant)
    int ks0 = ((lq) ^ (lr & 7)) * 8;          // K0 c=0 slot
    int ks1 = ((4 + lq) ^ (lr & 7)) * 8;      // K0 c=1 slot
    int k1off  = (lq >> 1) * 512 + (lq & 1) * 8;          // [Kh|Kl] variant
    int k1offb = ((lq >> 1) ^ 1) * 512 + (lq & 1) * 8;    // [Kl|Kh] variant
    int vsl = (lq ^ ((lr >> 1) & 3)) * 8;

    stage(0, 0);

    for (int t = 0; t < ntiles; t++) {
        int k0 = t * 32;
        __syncthreads();                         // drains vmcnt(0): tile t ready
        if (t + 1 < ntiles) stage(t + 1, (t + 1) & 1);
        u16* B = lds + (t & 1) * 10240;
        if (k0 <= qw0 + 15) {
            u16* bK0h = B;
            u16* bK0l = B + 2048;
            u16* bK1  = B + 4096;
            u16* bVh  = B + 5120;
            u16* bVl  = B + 7680;
            __builtin_amdgcn_s_setprio(1);
            // ---- S^T = K Q^T (A=K frag, B=Q frag) ----
            floatx4 s[2];
#pragma unroll
            for (int st = 0; st < 2; st++) {
                int krow = st * 16 + lr;
                bf16x8 kh0 = *(const bf16x8*)&bK0h[krow * 64 + ks0];
                bf16x8 kh1 = *(const bf16x8*)&bK0h[krow * 64 + ks1];
                bf16x8 kl0 = *(const bf16x8*)&bK0l[krow * 64 + ks0];
                bf16x8 kl1 = *(const bf16x8*)&bK0l[krow * 64 + ks1];
                bf16x8 k1f  = *(const bf16x8*)&bK1[krow * 16 + k1off];
                bf16x8 k1fb = *(const bf16x8*)&bK1[krow * 16 + k1offb];
                floatx4 sv = mk4(0.f);
                sv = __builtin_amdgcn_mfma_f32_16x16x32_bf16(kh0, qh[0], sv, 0, 0, 0);
                sv = __builtin_amdgcn_mfma_f32_16x16x32_bf16(kl0, qh[0], sv, 0, 0, 0);
                sv = __builtin_amdgcn_mfma_f32_16x16x32_bf16(kh0, ql[0], sv, 0, 0, 0);
                sv = __builtin_amdgcn_mfma_f32_16x16x32_bf16(kh1, qh[1], sv, 0, 0, 0);
                sv = __builtin_amdgcn_mfma_f32_16x16x32_bf16(kl1, qh[1], sv, 0, 0, 0);
                sv = __builtin_amdgcn_mfma_f32_16x16x32_bf16(kh1, ql[1], sv, 0, 0, 0);
                sv = __builtin_amdgcn_mfma_f32_16x16x32_bf16(k1f,  qta, sv, 0, 0, 0);
                sv = __builtin_amdgcn_mfma_f32_16x16x32_bf16(k1fb, qta, sv, 0, 0, 0);
                s[st] = sv;
            }
            // ---- causal mask (lane q = qw0+lr; keys k0+st*16+lq*4+r) ----
            if (k0 + 31 > qw0) {
                int qmy = qw0 + lr - k0 - lq * 4;   // key_local = st*16+r
#pragma unroll
                for (int r = 0; r < 4; r++) {
                    s[0][r] = (r <= qmy)      ? s[0][r] : -3.0e38f;
                    s[1][r] = (16 + r <= qmy) ? s[1][r] : -3.0e38f;
                }
            }
            // ---- online softmax (per-lane scalar, reduce over lq groups) ----
            float rm = fmaxf(fmaxf(fmaxf(s[0][0], s[0][1]), fmaxf(s[0][2], s[0][3])),
                             fmaxf(fmaxf(s[1][0], s[1][1]), fmaxf(s[1][2], s[1][3])));
            rm = fmaxf(rm, __shfl_xor(rm, 16));
            rm = fmaxf(rm, __shfl_xor(rm, 32));
            int need = rm > mrow + 8.f;
            if (__any(need)) {                 // rescale path (rare: defer-max)
                float mnew = fmaxf(mrow, rm);
                float alpha = __expf(mrow - mnew);
                mrow = mnew;
                lsum *= alpha;
                float at[4];
#pragma unroll
                for (int r = 0; r < 4; r++) at[r] = __shfl(alpha, lq * 4 + r);
#pragma unroll
                for (int nt = 0; nt < 5; nt++)
#pragma unroll
                    for (int r = 0; r < 4; r++) acc[nt][r] *= at[r];
            }
            floatx4 p0 = exp4(s[0] - mk4(mrow));
            floatx4 p1 = exp4(s[1] - mk4(mrow));
            floatx4 ps = p0 + p1;
            float rs = ps[0] + ps[1] + ps[2] + ps[3];
            rs += __shfl_xor(rs, 16);
            rs += __shfl_xor(rs, 32);
            lsum += rs;
            // ---- pack P in-register (matches key-interleaved V layout) ----
            bf16x8 pa;
            pa[0] = (__bf16)p0[0]; pa[1] = (__bf16)p0[1];
            pa[2] = (__bf16)p0[2]; pa[3] = (__bf16)p0[3];
            pa[4] = (__bf16)p1[0]; pa[5] = (__bf16)p1[1];
            pa[6] = (__bf16)p1[2]; pa[7] = (__bf16)p1[3];
            // ---- O += P V ----
#pragma unroll
            for (int nt = 0; nt < 5; nt++) {
                bf16x8 vh = *(const bf16x8*)&bVh[(nt * 16 + lr) * 32 + vsl];
                bf16x8 vl = *(const bf16x8*)&bVl[(nt * 16 + lr) * 32 + vsl];
                acc[nt] = __builtin_amdgcn_mfma_f32_16x16x32_bf16(pa, vh, acc[nt], 0, 0, 0);
                acc[nt] = __builtin_amdgcn_mfma_f32_16x16x32_bf16(pa, vl, acc[nt], 0, 0, 0);
            }
            __builtin_amdgcn_s_setprio(0);
        }
    }
    // ---- epilogue: O /= l, write split-bf16 ----
    {
        float il = 1.f / lsum;
        float inv[4];
#pragma unroll
        for (int r = 0; r < 4; r++) inv[r] = __shfl(il, lq * 4 + r);
#pragma unroll
        for (int nt = 0; nt < 5; nt++) {
#pragma unroll
            for (int r = 0; r < 4; r++) {
                float o = acc[nt][r] * inv[r];
                u16 hh = f2bf_bits(o);
                u16 ll = f2bf_bits(o - bf2f(hh));
                size_t row = rowbase + qw0 + lq * 4 + r;
                Oh_[row * HIDDEN + hoff + nt * 16 + lr] = hh;
                Ol_[row * HIDDEN + hoff + nt * 16 + lr] = ll;
            }
        }
    }
}

extern "C" void kernel_launch(void* const* d_in, const int* in_sizes, int n_in,
                              void* d_out, int out_size, void* d_ws, size_t ws_size,
                              hipStream_t stream) {
    const float* hidden = (const float*)d_in[0];
    const int* pos    = (const int*)d_in[2];
    const float* Wq   = (const float*)d_in[3];
    const float* Wk   = (const float*)d_in[4];
    const float* Wv   = (const float*)d_in[5];
    const float* Wo   = (const float*)d_in[6];

    const size_t NQ = (size_t)MROWS * HIDDEN;          // 10,485,760 elems
    float* ws = (float*)d_ws;
    float* Qb = ws;                                     // [0, NQ) fp32
    float* Kb = ws + NQ;                                // [NQ, 2NQ) fp32
    float* Vb = ws + 2 * NQ;                            // [2NQ, 3NQ) fp32
    u16* Ah  = (u16*)(ws + 3 * NQ);                     // NQ u16
    u16* Al  = Ah + NQ;                                 // NQ u16
    u16* WTh = Al + NQ;                                 // 2560^2 u16
    u16* WTl = WTh + (size_t)HIDDEN * HIDDEN;           // 2560^2 u16
    u16* Vth = Ah;                    // after QKV GEMMs, Ah/Al free
    u16* Vtl = Al;
    u16* Qh  = (u16*)Vb;              // after vtrans, Vb free
    u16* Ql  = Qh + NQ;
    u16* Kh  = (u16*)Qb;              // after Q split, Qb free
    u16* Kl  = Kh + NQ;
    u16* Oh  = (u16*)Kb;              // after K split, Kb free
    u16* Ol  = Oh + NQ;

    const float SC = 0.11180339887498949f;              // 1/sqrt(80)

    dim3 blk(256);
    dim3 wgrid(HIDDEN / 64, HIDDEN / 64);
    dim3 ggrid(HIDDEN / 128, MROWS / 128);

    split_x<<<dim3(NQ / 1024), blk, 0, stream>>>(hidden, Ah, Al, 1.f);
    split_wt<<<wgrid, blk, 0, stream>>>(Wq, WTh, WTl);
    gemm_bt2<<<ggrid, blk, 0, stream>>>(Ah, Al, WTh, WTl, Qb);
    split_wt<<<wgrid, blk, 0, stream>>>(Wk, WTh, WTl);
    gemm_bt2<<<ggrid, blk, 0, stream>>>(Ah, Al, WTh, WTl, Kb);
    split_wt<<<wgrid, blk, 0, stream>>>(Wv, WTh, WTl);
    gemm_bt2<<<ggrid, blk, 0, stream>>>(Ah, Al, WTh, WTl, Vb);
    rope_k<<<dim3(MROWS * NHEADS / 256), blk, 0, stream>>>(Qb, Kb, pos);
    vtrans<<<dim3(BATCH * NHEADS, SEQ / 64), blk, 0, stream>>>(Vb, Vth, Vtl);
    split_x<<<dim3(NQ / 1024), blk, 0, stream>>>(Qb, Qh, Ql, SC);
    split_x<<<dim3(NQ / 1024), blk, 0, stream>>>(Kb, Kh, Kl, 1.f);
    attn_mfma<<<dim3(BATCH * NHEADS, SEQ / QB), blk, 0, stream>>>(Qh, Ql, Kh, Kl,
                                                                  Vth, Vtl, Oh, Ol);
    split_wt<<<wgrid, blk, 0, stream>>>(Wo, WTh, WTl);
    gemm_bt2<<<ggrid, blk, 0, stream>>>(Oh, Ol, WTh, WTl, (float*)d_out);
}